// Round 2
// baseline (6137.149 us; speedup 1.0000x reference)
//
#include <hip/hip_runtime.h>
#include <hip/hip_bf16.h>

#define N_NODES 200000
#define N_EDGES 600000
#define N_GRAPHS 4000
#define EMB 128
#define LAYERS 5
#define BN_EPS 1e-5f

// ---------------------------------------------------------------------------
// BN precompute: S = gamma/sqrt(var+eps), T = beta - mean*S   (5*128 each)
// ---------------------------------------------------------------------------
__global__ void bnprep(const float* __restrict__ mean, const float* __restrict__ var,
                       const float* __restrict__ gamma, const float* __restrict__ beta,
                       float* __restrict__ S, float* __restrict__ T) {
    int i = blockIdx.x * blockDim.x + threadIdx.x;
    if (i < LAYERS * EMB) {
        float s = gamma[i] / sqrtf(var[i] + BN_EPS);
        S[i] = s;
        T[i] = beta[i] - mean[i] * s;
    }
}

// ---------------------------------------------------------------------------
// Atom encoder: h[n][c] = sum_f atom_emb[f][x[n][f]][c]
// 32 lanes per node (float4 per lane), 8 nodes per 256-thread block
// ---------------------------------------------------------------------------
__global__ __launch_bounds__(256) void encoder(const int* __restrict__ x,
                                               const float* __restrict__ aemb,
                                               float* __restrict__ H) {
    const int g  = threadIdx.x & 31;
    const int n  = blockIdx.x * 8 + (threadIdx.x >> 5);
    if (n >= N_NODES) return;
    const int c0 = g * 4;
    float4 acc = make_float4(0.f, 0.f, 0.f, 0.f);
#pragma unroll
    for (int f = 0; f < 9; ++f) {
        const int v = x[n * 9 + f];
        const float4 e = *(const float4*)&aemb[(size_t)(f * 64 + v) * EMB + c0];
        acc.x += e.x; acc.y += e.y; acc.z += e.z; acc.w += e.w;
    }
    *(float4*)&H[(size_t)n * EMB + c0] = acc;
}

// ---------------------------------------------------------------------------
// Degree count (src side), float accumulate
// ---------------------------------------------------------------------------
__global__ void deg_count(const int* __restrict__ srcs, float* __restrict__ deg) {
    int e = blockIdx.x * blockDim.x + threadIdx.x;
    if (e < N_EDGES) unsafeAtomicAdd(&deg[srcs[e]], 1.0f);
}

// norm[e] = (deg[src]+1)^-0.5 * (deg[dst]+1)^-0.5
__global__ void norm_k(const int* __restrict__ srcs, const int* __restrict__ dsts,
                       const float* __restrict__ deg, float* __restrict__ nrm) {
    int e = blockIdx.x * blockDim.x + threadIdx.x;
    if (e < N_EDGES) {
        float ds = deg[srcs[e]] + 1.0f;
        float dd = deg[dsts[e]] + 1.0f;
        nrm[e] = (1.0f / sqrtf(ds)) * (1.0f / sqrtf(dd));
    }
}

// ---------------------------------------------------------------------------
// Layer GEMM (IN-PLACE over A): XL = act(A) @ W + b ; SELF = relu(XL+root)/(deg+1)
// act(A) = (bnS ? relu(A*bnS + bnT) : A)   -- folds previous layer's BN+ReLU
// Each block owns 64 rows: stages act(A) rows to LDS, syncs, computes from LDS,
// then writes XL back over the SAME rows -> A and XL may alias (no __restrict__).
// 256 threads: 8 row-threads x 32 col-threads, each 8 rows x 4 cols.
// ---------------------------------------------------------------------------
__global__ __launch_bounds__(256) void gemm_layer(
    const float* A, const float* __restrict__ bnS, const float* __restrict__ bnT,
    const float* __restrict__ W, const float* __restrict__ bias, const float* __restrict__ root,
    const float* __restrict__ deg, float* XL, float* SELF) {
    __shared__ float Atile[64][EMB];
    const int tid  = threadIdx.x;
    const size_t rows = (size_t)blockIdx.x * 64;

    // stage A tile with fused BN+ReLU
#pragma unroll
    for (int i = 0; i < 8; ++i) {
        const int v   = tid + i * 256;          // float4 index in tile
        const int row = v >> 5;
        const int c4  = (v & 31) * 4;
        float4 a = *(const float4*)&A[(rows + row) * EMB + c4];
        if (bnS) {
            const float4 s = *(const float4*)&bnS[c4];
            const float4 t = *(const float4*)&bnT[c4];
            a.x = fmaxf(fmaf(a.x, s.x, t.x), 0.f);
            a.y = fmaxf(fmaf(a.y, s.y, t.y), 0.f);
            a.z = fmaxf(fmaf(a.z, s.z, t.z), 0.f);
            a.w = fmaxf(fmaf(a.w, s.w, t.w), 0.f);
        }
        *(float4*)&Atile[row][c4] = a;
    }
    __syncthreads();

    const int tx = tid & 31;
    const int ty = tid >> 5;
    const int c0 = tx * 4;

    float4 acc[8];
#pragma unroll
    for (int r = 0; r < 8; ++r) acc[r] = make_float4(0.f, 0.f, 0.f, 0.f);

#pragma unroll 4
    for (int k = 0; k < EMB; ++k) {
        const float4 w = *(const float4*)&W[(size_t)k * EMB + c0];
#pragma unroll
        for (int r = 0; r < 8; ++r) {
            const float a = Atile[ty * 8 + r][k];
            acc[r].x = fmaf(a, w.x, acc[r].x);
            acc[r].y = fmaf(a, w.y, acc[r].y);
            acc[r].z = fmaf(a, w.z, acc[r].z);
            acc[r].w = fmaf(a, w.w, acc[r].w);
        }
    }

    const float4 b4 = *(const float4*)&bias[c0];
    const float4 r4 = *(const float4*)&root[c0];
#pragma unroll
    for (int r = 0; r < 8; ++r) {
        const size_t R = rows + ty * 8 + r;
        const float dinv = 1.0f / (deg[R] + 1.0f);
        float4 o;
        o.x = acc[r].x + b4.x; o.y = acc[r].y + b4.y;
        o.z = acc[r].z + b4.z; o.w = acc[r].w + b4.w;
        *(float4*)&XL[R * EMB + c0] = o;
        float4 s;
        s.x = fmaxf(o.x + r4.x, 0.f) * dinv;
        s.y = fmaxf(o.y + r4.y, 0.f) * dinv;
        s.z = fmaxf(o.z + r4.z, 0.f) * dinv;
        s.w = fmaxf(o.w + r4.w, 0.f) * dinv;
        *(float4*)&SELF[R * EMB + c0] = s;
    }
}

// ---------------------------------------------------------------------------
// Edge aggregation: OUT[dst] += norm[e] * relu(XL[src] + bond_emb(edge_attr))
// 32 lanes per edge (float4 per lane), 8 edges per block
// ---------------------------------------------------------------------------
__global__ __launch_bounds__(256) void edge_agg(
    const int* __restrict__ srcs, const int* __restrict__ dsts,
    const int* __restrict__ eattr, const float* __restrict__ nrm,
    const float* __restrict__ bond, const float* __restrict__ XL,
    float* __restrict__ OUT) {
    const int g = threadIdx.x & 31;
    const int e = blockIdx.x * 8 + (threadIdx.x >> 5);
    if (e >= N_EDGES) return;
    const int s  = srcs[e];
    const int d  = dsts[e];
    const float n = nrm[e];
    const int a0 = eattr[e * 3 + 0];
    const int a1 = eattr[e * 3 + 1];
    const int a2 = eattr[e * 3 + 2];
    const int c0 = g * 4;
    const float4 e0 = *(const float4*)&bond[(size_t)(0 * 8 + a0) * EMB + c0];
    const float4 e1 = *(const float4*)&bond[(size_t)(1 * 8 + a1) * EMB + c0];
    const float4 e2 = *(const float4*)&bond[(size_t)(2 * 8 + a2) * EMB + c0];
    const float4 x  = *(const float4*)&XL[(size_t)s * EMB + c0];
    float4 m;
    m.x = fmaxf(x.x + e0.x + e1.x + e2.x, 0.f) * n;
    m.y = fmaxf(x.y + e0.y + e1.y + e2.y, 0.f) * n;
    m.z = fmaxf(x.z + e0.z + e1.z + e2.z, 0.f) * n;
    m.w = fmaxf(x.w + e0.w + e1.w + e2.w, 0.f) * n;
    float* o = &OUT[(size_t)d * EMB + c0];
    unsafeAtomicAdd(o + 0, m.x);
    unsafeAtomicAdd(o + 1, m.y);
    unsafeAtomicAdd(o + 2, m.z);
    unsafeAtomicAdd(o + 3, m.w);
}

// ---------------------------------------------------------------------------
// Pool: HG[batch[n]] += BN4(H[n])   (no relu on last layer)
// ---------------------------------------------------------------------------
__global__ __launch_bounds__(256) void pool(const float* __restrict__ H,
                                            const float* __restrict__ S4, const float* __restrict__ T4,
                                            const int* __restrict__ batch, float* __restrict__ HG) {
    const int g = threadIdx.x & 31;
    const int n = blockIdx.x * 8 + (threadIdx.x >> 5);
    if (n >= N_NODES) return;
    const int b  = batch[n];
    const int c0 = g * 4;
    const float4 s = *(const float4*)&S4[c0];
    const float4 t = *(const float4*)&T4[c0];
    const float4 v = *(const float4*)&H[(size_t)n * EMB + c0];
    float* o = &HG[(size_t)b * EMB + c0];
    unsafeAtomicAdd(o + 0, fmaf(v.x, s.x, t.x));
    unsafeAtomicAdd(o + 1, fmaf(v.y, s.y, t.y));
    unsafeAtomicAdd(o + 2, fmaf(v.z, s.z, t.z));
    unsafeAtomicAdd(o + 3, fmaf(v.w, s.w, t.w));
}

// ---------------------------------------------------------------------------
// Head: OUT[g] = HG[g] @ headW + headb
// ---------------------------------------------------------------------------
__global__ __launch_bounds__(128) void head(const float* __restrict__ HG,
                                            const float* __restrict__ HW,
                                            const float* __restrict__ hb,
                                            float* __restrict__ OUT) {
    __shared__ float hr[EMB];
    const int gph = blockIdx.x;
    const int t   = threadIdx.x;
    hr[t] = HG[(size_t)gph * EMB + t];
    __syncthreads();
    float acc = hb[t];
#pragma unroll 8
    for (int k = 0; k < EMB; ++k) acc = fmaf(hr[k], HW[(size_t)k * EMB + t], acc);
    OUT[(size_t)gph * EMB + t] = acc;
}

extern "C" void kernel_launch(void* const* d_in, const int* in_sizes, int n_in,
                              void* d_out, int out_size, void* d_ws, size_t ws_size,
                              hipStream_t stream) {
    const int*   x     = (const int*)d_in[0];
    const int*   ei    = (const int*)d_in[1];    // [2, E] row-major: src then dst
    const int*   ea    = (const int*)d_in[2];    // [E, 3]
    const int*   batch = (const int*)d_in[3];
    const float* aemb  = (const float*)d_in[4];  // [9, 64, 128]
    const float* bemb  = (const float*)d_in[5];  // [5, 3, 8, 128]
    const float* W     = (const float*)d_in[6];  // [5, 128, 128]
    const float* b     = (const float*)d_in[7];
    const float* root  = (const float*)d_in[8];
    const float* bnm   = (const float*)d_in[9];
    const float* bnv   = (const float*)d_in[10];
    const float* bng   = (const float*)d_in[11];
    const float* bnb   = (const float*)d_in[12];
    const float* hW    = (const float*)d_in[13]; // [128, 128]
    const float* hb    = (const float*)d_in[14];
    float* out = (float*)d_out;

    const size_t NF = (size_t)N_NODES * EMB;
    // ws layout: bufA | bufB | deg | nrm | hg | S | T
    const size_t need = (2 * NF + N_NODES + N_EDGES + (size_t)N_GRAPHS * EMB
                         + 2 * LAYERS * EMB) * sizeof(float);
    if (ws_size < need) return;  // defensive: fail validation cleanly, don't fault

    float* ws   = (float*)d_ws;
    float* bufA = ws;
    float* bufB = bufA + NF;
    float* deg  = bufB + NF;
    float* nrm  = deg + N_NODES;
    float* hg   = nrm + N_EDGES;
    float* S    = hg + (size_t)N_GRAPHS * EMB;
    float* T    = S + LAYERS * EMB;

    hipMemsetAsync(deg, 0, N_NODES * sizeof(float), stream);
    hipMemsetAsync(hg, 0, (size_t)N_GRAPHS * EMB * sizeof(float), stream);

    bnprep<<<3, 256, 0, stream>>>(bnm, bnv, bng, bnb, S, T);
    encoder<<<N_NODES / 8, 256, 0, stream>>>(x, aemb, bufA);
    deg_count<<<(N_EDGES + 255) / 256, 256, 0, stream>>>(ei, deg);
    norm_k<<<(N_EDGES + 255) / 256, 256, 0, stream>>>(ei, ei + N_EDGES, deg, nrm);

    // Ping-pong: layer l reads `in`, writes XL in-place over `in`, seeds SELF
    // into `other`; edge_agg accumulates into `other`; next layer's in = other.
    float* in    = bufA;
    float* other = bufB;
    for (int l = 0; l < LAYERS; ++l) {
        gemm_layer<<<N_NODES / 64, 256, 0, stream>>>(
            in, l ? S + (l - 1) * EMB : nullptr, l ? T + (l - 1) * EMB : nullptr,
            W + (size_t)l * EMB * EMB, b + l * EMB, root + l * EMB, deg,
            /*XL=*/in, /*SELF=*/other);
        edge_agg<<<(N_EDGES + 7) / 8, 256, 0, stream>>>(
            ei, ei + N_EDGES, ea, nrm, bemb + (size_t)l * 3 * 8 * EMB, /*XL=*/in, /*OUT=*/other);
        float* t0 = in; in = other; other = t0;
    }

    pool<<<N_NODES / 8, 256, 0, stream>>>(in, S + 4 * EMB, T + 4 * EMB, batch, hg);
    head<<<N_GRAPHS, 128, 0, stream>>>(hg, hW, hb, out);
}

// Round 3
// 1507.886 us; speedup vs baseline: 4.0700x; 4.0700x over previous
//
#include <hip/hip_runtime.h>
#include <hip/hip_bf16.h>

#define N_NODES 200000
#define N_EDGES 600000
#define N_GRAPHS 4000
#define EMB 128
#define LAYERS 5
#define BN_EPS 1e-5f

#define SCAN_CHUNK 2048                   // 256 threads x 8
#define N_CHUNKS ((N_NODES + SCAN_CHUNK - 1) / SCAN_CHUNK)   // 98

// ---------------------------------------------------------------------------
// BN precompute: S = gamma/sqrt(var+eps), T = beta - mean*S
// ---------------------------------------------------------------------------
__global__ void bnprep(const float* __restrict__ mean, const float* __restrict__ var,
                       const float* __restrict__ gamma, const float* __restrict__ beta,
                       float* __restrict__ S, float* __restrict__ T) {
    int i = blockIdx.x * blockDim.x + threadIdx.x;
    if (i < LAYERS * EMB) {
        float s = gamma[i] / sqrtf(var[i] + BN_EPS);
        S[i] = s;
        T[i] = beta[i] - mean[i] * s;
    }
}

// ---------------------------------------------------------------------------
// Bond-combo table: combo[l][c][ch] = sum_f bond_emb[l,f,a_f(c)][ch], c packs
// (a0,a1,a2) as a0|a1<<3|a2<<6. 512 combos x 128 ch x 5 layers = 1.3 MB.
// ---------------------------------------------------------------------------
__global__ void combo_k(const float* __restrict__ bemb, float* __restrict__ combo) {
    const int l = blockIdx.x >> 9;
    const int c = blockIdx.x & 511;
    const int a0 = c & 7, a1 = (c >> 3) & 7, a2 = c >> 6;
    const int t = threadIdx.x;
    combo[(size_t)blockIdx.x * EMB + t] =
        bemb[(size_t)((l * 3 + 0) * 8 + a0) * EMB + t] +
        bemb[(size_t)((l * 3 + 1) * 8 + a1) * EMB + t] +
        bemb[(size_t)((l * 3 + 2) * 8 + a2) * EMB + t];
}

// ---------------------------------------------------------------------------
// Atom encoder
// ---------------------------------------------------------------------------
__global__ __launch_bounds__(256) void encoder(const int* __restrict__ x,
                                               const float* __restrict__ aemb,
                                               float* __restrict__ H) {
    const int g  = threadIdx.x & 31;
    const int n  = blockIdx.x * 8 + (threadIdx.x >> 5);
    if (n >= N_NODES) return;
    const int c0 = g * 4;
    float4 acc = make_float4(0.f, 0.f, 0.f, 0.f);
#pragma unroll
    for (int f = 0; f < 9; ++f) {
        const int v = x[n * 9 + f];
        const float4 e = *(const float4*)&aemb[(size_t)(f * 64 + v) * EMB + c0];
        acc.x += e.x; acc.y += e.y; acc.z += e.z; acc.w += e.w;
    }
    *(float4*)&H[(size_t)n * EMB + c0] = acc;
}

// ---------------------------------------------------------------------------
// Edge histogram: src-degree (for norm & self term) and dst-degree (for CSR)
// ---------------------------------------------------------------------------
__global__ void count_k(const int* __restrict__ srcs, const int* __restrict__ dsts,
                        int* __restrict__ dsrc, int* __restrict__ ddst) {
    int e = blockIdx.x * blockDim.x + threadIdx.x;
    if (e < N_EDGES) {
        atomicAdd(&dsrc[srcs[e]], 1);
        atomicAdd(&ddst[dsts[e]], 1);
    }
}

// ---------------------------------------------------------------------------
// 3-phase exclusive scan of ddst -> rowptr
// ---------------------------------------------------------------------------
__global__ __launch_bounds__(256) void scan1(const int* __restrict__ deg, int* __restrict__ partial) {
    __shared__ int sd[256];
    const int base = blockIdx.x * SCAN_CHUNK + threadIdx.x * 8;
    int s = 0;
#pragma unroll
    for (int i = 0; i < 8; ++i) { int idx = base + i; s += (idx < N_NODES) ? deg[idx] : 0; }
    sd[threadIdx.x] = s; __syncthreads();
    for (int off = 128; off > 0; off >>= 1) {
        if (threadIdx.x < off) sd[threadIdx.x] += sd[threadIdx.x + off];
        __syncthreads();
    }
    if (threadIdx.x == 0) partial[blockIdx.x] = sd[0];
}

__global__ void scan2(int* __restrict__ partial) {
    if (threadIdx.x == 0) {
        int acc = 0;
        for (int i = 0; i < N_CHUNKS; ++i) { int v = partial[i]; partial[i] = acc; acc += v; }
    }
}

__global__ __launch_bounds__(256) void scan3(const int* __restrict__ deg,
                                             const int* __restrict__ partial,
                                             int* __restrict__ rowptr) {
    __shared__ int sd[256];
    const int tid = threadIdx.x;
    const int base = blockIdx.x * SCAN_CHUNK + tid * 8;
    int loc[8]; int s = 0;
#pragma unroll
    for (int i = 0; i < 8; ++i) { int idx = base + i; loc[i] = (idx < N_NODES) ? deg[idx] : 0; s += loc[i]; }
    sd[tid] = s; __syncthreads();
    for (int off = 1; off < 256; off <<= 1) {
        int v = (tid >= off) ? sd[tid - off] : 0;
        __syncthreads();
        sd[tid] += v;
        __syncthreads();
    }
    int excl = partial[blockIdx.x] + sd[tid] - s;
#pragma unroll
    for (int i = 0; i < 8; ++i) {
        int idx = base + i;
        if (idx < N_NODES) { rowptr[idx] = excl; excl += loc[i]; }
    }
    if (blockIdx.x == 0 && tid == 0) rowptr[N_NODES] = N_EDGES;
}

// ---------------------------------------------------------------------------
// Scatter edges into dst-CSR. Record: epk = src | combo<<18 ; enrm = norm.
// ---------------------------------------------------------------------------
__global__ void scatter_k(const int* __restrict__ srcs, const int* __restrict__ dsts,
                          const int* __restrict__ eattr, const int* __restrict__ dsrc,
                          const int* __restrict__ rowptr, int* __restrict__ fill,
                          int* __restrict__ epk, float* __restrict__ enrm) {
    int e = blockIdx.x * blockDim.x + threadIdx.x;
    if (e >= N_EDGES) return;
    const int s = srcs[e];
    const int d = dsts[e];
    const int pos = rowptr[d] + atomicAdd(&fill[d], 1);
    const int c = eattr[e * 3] | (eattr[e * 3 + 1] << 3) | (eattr[e * 3 + 2] << 6);
    epk[pos] = s | (c << 18);
    enrm[pos] = rsqrtf((float)(dsrc[s] + 1) * (float)(dsrc[d] + 1));
}

// ---------------------------------------------------------------------------
// Layer GEMM (IN-PLACE over A): XL = act(A) @ W + b ; SELF = relu(XL+root)/(deg+1)
// act(A) = (bnS ? relu(A*bnS + bnT) : A). A/XL alias (block-private rows).
// ---------------------------------------------------------------------------
__global__ __launch_bounds__(256) void gemm_layer(
    const float* A, const float* __restrict__ bnS, const float* __restrict__ bnT,
    const float* __restrict__ W, const float* __restrict__ bias, const float* __restrict__ root,
    const int* __restrict__ dsrc, float* XL, float* SELF) {
    __shared__ float Atile[64][EMB];
    const int tid  = threadIdx.x;
    const size_t rows = (size_t)blockIdx.x * 64;

#pragma unroll
    for (int i = 0; i < 8; ++i) {
        const int v   = tid + i * 256;
        const int row = v >> 5;
        const int c4  = (v & 31) * 4;
        float4 a = *(const float4*)&A[(rows + row) * EMB + c4];
        if (bnS) {
            const float4 s = *(const float4*)&bnS[c4];
            const float4 t = *(const float4*)&bnT[c4];
            a.x = fmaxf(fmaf(a.x, s.x, t.x), 0.f);
            a.y = fmaxf(fmaf(a.y, s.y, t.y), 0.f);
            a.z = fmaxf(fmaf(a.z, s.z, t.z), 0.f);
            a.w = fmaxf(fmaf(a.w, s.w, t.w), 0.f);
        }
        *(float4*)&Atile[row][c4] = a;
    }
    __syncthreads();

    const int tx = tid & 31;
    const int ty = tid >> 5;
    const int c0 = tx * 4;

    float4 acc[8];
#pragma unroll
    for (int r = 0; r < 8; ++r) acc[r] = make_float4(0.f, 0.f, 0.f, 0.f);

#pragma unroll 4
    for (int k = 0; k < EMB; ++k) {
        const float4 w = *(const float4*)&W[(size_t)k * EMB + c0];
#pragma unroll
        for (int r = 0; r < 8; ++r) {
            const float a = Atile[ty * 8 + r][k];
            acc[r].x = fmaf(a, w.x, acc[r].x);
            acc[r].y = fmaf(a, w.y, acc[r].y);
            acc[r].z = fmaf(a, w.z, acc[r].z);
            acc[r].w = fmaf(a, w.w, acc[r].w);
        }
    }

    const float4 b4 = *(const float4*)&bias[c0];
    const float4 r4 = *(const float4*)&root[c0];
#pragma unroll
    for (int r = 0; r < 8; ++r) {
        const size_t R = rows + ty * 8 + r;
        const float dinv = 1.0f / (float)(dsrc[R] + 1);
        float4 o;
        o.x = acc[r].x + b4.x; o.y = acc[r].y + b4.y;
        o.z = acc[r].z + b4.z; o.w = acc[r].w + b4.w;
        *(float4*)&XL[R * EMB + c0] = o;
        float4 s;
        s.x = fmaxf(o.x + r4.x, 0.f) * dinv;
        s.y = fmaxf(o.y + r4.y, 0.f) * dinv;
        s.z = fmaxf(o.z + r4.z, 0.f) * dinv;
        s.w = fmaxf(o.w + r4.w, 0.f) * dinv;
        *(float4*)&SELF[R * EMB + c0] = s;
    }
}

// ---------------------------------------------------------------------------
// Edge aggregation as GATHER (no atomics): half-wave per dst node.
// OUT row is pre-seeded with SELF by gemm_layer; accumulate incoming messages
// from the dst-CSR and write the row back once.
// ---------------------------------------------------------------------------
__global__ __launch_bounds__(256) void edge_gather(
    const int* __restrict__ rowptr, const int* __restrict__ epk,
    const float* __restrict__ enrm, const float* __restrict__ combo,
    const float* __restrict__ XL, float* __restrict__ OUT) {
    const int g = threadIdx.x & 31;
    const int n = blockIdx.x * 8 + (threadIdx.x >> 5);
    if (n >= N_NODES) return;
    const int c0 = g * 4;
    float4 acc = *(const float4*)&OUT[(size_t)n * EMB + c0];   // SELF seed
    const int beg = rowptr[n];
    const int end = rowptr[n + 1];
    for (int i = beg; i < end; ++i) {
        const int  pk = epk[i];
        const float w = enrm[i];
        const int  s  = pk & 0x3FFFF;
        const int  c  = pk >> 18;
        const float4 x  = *(const float4*)&XL[(size_t)s * EMB + c0];
        const float4 cb = *(const float4*)&combo[(size_t)c * EMB + c0];
        acc.x += fmaxf(x.x + cb.x, 0.f) * w;
        acc.y += fmaxf(x.y + cb.y, 0.f) * w;
        acc.z += fmaxf(x.z + cb.z, 0.f) * w;
        acc.w += fmaxf(x.w + cb.w, 0.f) * w;
    }
    *(float4*)&OUT[(size_t)n * EMB + c0] = acc;
}

// ---------------------------------------------------------------------------
// Pool: HG[batch[n]] += BN4(H[n])
// ---------------------------------------------------------------------------
__global__ __launch_bounds__(256) void pool(const float* __restrict__ H,
                                            const float* __restrict__ S4, const float* __restrict__ T4,
                                            const int* __restrict__ batch, float* __restrict__ HG) {
    const int g = threadIdx.x & 31;
    const int n = blockIdx.x * 8 + (threadIdx.x >> 5);
    if (n >= N_NODES) return;
    const int b  = batch[n];
    const int c0 = g * 4;
    const float4 s = *(const float4*)&S4[c0];
    const float4 t = *(const float4*)&T4[c0];
    const float4 v = *(const float4*)&H[(size_t)n * EMB + c0];
    float* o = &HG[(size_t)b * EMB + c0];
    unsafeAtomicAdd(o + 0, fmaf(v.x, s.x, t.x));
    unsafeAtomicAdd(o + 1, fmaf(v.y, s.y, t.y));
    unsafeAtomicAdd(o + 2, fmaf(v.z, s.z, t.z));
    unsafeAtomicAdd(o + 3, fmaf(v.w, s.w, t.w));
}

// ---------------------------------------------------------------------------
// Head: OUT[g] = HG[g] @ headW + headb
// ---------------------------------------------------------------------------
__global__ __launch_bounds__(128) void head(const float* __restrict__ HG,
                                            const float* __restrict__ HW,
                                            const float* __restrict__ hb,
                                            float* __restrict__ OUT) {
    __shared__ float hr[EMB];
    const int gph = blockIdx.x;
    const int t   = threadIdx.x;
    hr[t] = HG[(size_t)gph * EMB + t];
    __syncthreads();
    float acc = hb[t];
#pragma unroll 8
    for (int k = 0; k < EMB; ++k) acc = fmaf(hr[k], HW[(size_t)k * EMB + t], acc);
    OUT[(size_t)gph * EMB + t] = acc;
}

extern "C" void kernel_launch(void* const* d_in, const int* in_sizes, int n_in,
                              void* d_out, int out_size, void* d_ws, size_t ws_size,
                              hipStream_t stream) {
    const int*   x     = (const int*)d_in[0];
    const int*   ei    = (const int*)d_in[1];    // [2, E]: src then dst
    const int*   ea    = (const int*)d_in[2];    // [E, 3]
    const int*   batch = (const int*)d_in[3];
    const float* aemb  = (const float*)d_in[4];
    const float* bemb  = (const float*)d_in[5];
    const float* W     = (const float*)d_in[6];
    const float* b     = (const float*)d_in[7];
    const float* root  = (const float*)d_in[8];
    const float* bnm   = (const float*)d_in[9];
    const float* bnv   = (const float*)d_in[10];
    const float* bng   = (const float*)d_in[11];
    const float* bnb   = (const float*)d_in[12];
    const float* hW    = (const float*)d_in[13];
    const float* hb    = (const float*)d_in[14];
    float* out = (float*)d_out;

    const size_t NF = (size_t)N_NODES * EMB;
    const size_t n_float = 2 * NF + (size_t)LAYERS * 512 * EMB + (size_t)N_GRAPHS * EMB
                         + 2 * LAYERS * EMB + N_EDGES;
    const size_t n_int   = 3 * (size_t)N_NODES + (N_NODES + 4) + 128 + N_EDGES;
    const size_t need = (n_float + n_int) * sizeof(float);
    if (ws_size < need) return;  // defensive: fail cleanly, don't fault

    float* f     = (float*)d_ws;
    float* bufA  = f;                          f += NF;
    float* bufB  = f;                          f += NF;
    float* combo = f;                          f += (size_t)LAYERS * 512 * EMB;
    float* hg    = f;                          f += (size_t)N_GRAPHS * EMB;
    float* S     = f;                          f += LAYERS * EMB;
    float* T     = f;                          f += LAYERS * EMB;
    float* enrm  = f;                          f += N_EDGES;
    int*   ip    = (int*)f;
    int*   dsrc    = ip;                       ip += N_NODES;
    int*   ddst    = ip;                       ip += N_NODES;
    int*   fill    = ip;                       ip += N_NODES;
    int*   rowptr  = ip;                       ip += N_NODES + 4;
    int*   partial = ip;                       ip += 128;
    int*   epk     = ip;                       ip += N_EDGES;

    // zero: dsrc, ddst, fill (contiguous) + hg
    hipMemsetAsync(dsrc, 0, 3 * (size_t)N_NODES * sizeof(int), stream);
    hipMemsetAsync(hg, 0, (size_t)N_GRAPHS * EMB * sizeof(float), stream);

    bnprep<<<3, 256, 0, stream>>>(bnm, bnv, bng, bnb, S, T);
    combo_k<<<LAYERS * 512, EMB, 0, stream>>>(bemb, combo);
    encoder<<<N_NODES / 8, 256, 0, stream>>>(x, aemb, bufA);
    count_k<<<(N_EDGES + 255) / 256, 256, 0, stream>>>(ei, ei + N_EDGES, dsrc, ddst);
    scan1<<<N_CHUNKS, 256, 0, stream>>>(ddst, partial);
    scan2<<<1, 64, 0, stream>>>(partial);
    scan3<<<N_CHUNKS, 256, 0, stream>>>(ddst, partial, rowptr);
    scatter_k<<<(N_EDGES + 255) / 256, 256, 0, stream>>>(ei, ei + N_EDGES, ea, dsrc,
                                                         rowptr, fill, epk, enrm);

    // Ping-pong: layer l reads `in`, writes XL in-place over `in`, seeds SELF
    // into `other`; edge_gather accumulates into `other`; next in = other.
    float* in    = bufA;
    float* other = bufB;
    for (int l = 0; l < LAYERS; ++l) {
        gemm_layer<<<N_NODES / 64, 256, 0, stream>>>(
            in, l ? S + (l - 1) * EMB : nullptr, l ? T + (l - 1) * EMB : nullptr,
            W + (size_t)l * EMB * EMB, b + l * EMB, root + l * EMB, dsrc,
            /*XL=*/in, /*SELF=*/other);
        edge_gather<<<N_NODES / 8, 256, 0, stream>>>(
            rowptr, epk, enrm, combo + (size_t)l * 512 * EMB, /*XL=*/in, /*OUT=*/other);
        float* t0 = in; in = other; other = t0;
    }

    pool<<<N_NODES / 8, 256, 0, stream>>>(in, S + 4 * EMB, T + 4 * EMB, batch, hg);
    head<<<N_GRAPHS, 128, 0, stream>>>(hg, hW, hb, out);
}

// Round 4
// 1142.512 us; speedup vs baseline: 5.3716x; 1.3198x over previous
//
#include <hip/hip_runtime.h>
#include <hip/hip_bf16.h>

#define N_NODES 200000
#define N_EDGES 600000
#define N_GRAPHS 4000
#define EMB 128
#define LAYERS 5
#define BN_EPS 1e-5f

#define SCAN_CHUNK 2048                   // 256 threads x 8
#define N_CHUNKS ((N_NODES + SCAN_CHUNK - 1) / SCAN_CHUNK)   // 98

// ---------------------------------------------------------------------------
// BN precompute: S = gamma/sqrt(var+eps), T = beta - mean*S
// ---------------------------------------------------------------------------
__global__ void bnprep(const float* __restrict__ mean, const float* __restrict__ var,
                       const float* __restrict__ gamma, const float* __restrict__ beta,
                       float* __restrict__ S, float* __restrict__ T) {
    int i = blockIdx.x * blockDim.x + threadIdx.x;
    if (i < LAYERS * EMB) {
        float s = gamma[i] / sqrtf(var[i] + BN_EPS);
        S[i] = s;
        T[i] = beta[i] - mean[i] * s;
    }
}

// ---------------------------------------------------------------------------
// Bond-combo table: combo[l][c][ch] = sum_f bond_emb[l,f,a_f(c)][ch]
// ---------------------------------------------------------------------------
__global__ void combo_k(const float* __restrict__ bemb, float* __restrict__ combo) {
    const int l = blockIdx.x >> 9;
    const int c = blockIdx.x & 511;
    const int a0 = c & 7, a1 = (c >> 3) & 7, a2 = c >> 6;
    const int t = threadIdx.x;
    combo[(size_t)blockIdx.x * EMB + t] =
        bemb[(size_t)((l * 3 + 0) * 8 + a0) * EMB + t] +
        bemb[(size_t)((l * 3 + 1) * 8 + a1) * EMB + t] +
        bemb[(size_t)((l * 3 + 2) * 8 + a2) * EMB + t];
}

// ---------------------------------------------------------------------------
// Atom encoder
// ---------------------------------------------------------------------------
__global__ __launch_bounds__(256) void encoder(const int* __restrict__ x,
                                               const float* __restrict__ aemb,
                                               float* __restrict__ H) {
    const int g  = threadIdx.x & 31;
    const int n  = blockIdx.x * 8 + (threadIdx.x >> 5);
    if (n >= N_NODES) return;
    const int c0 = g * 4;
    float4 acc = make_float4(0.f, 0.f, 0.f, 0.f);
#pragma unroll
    for (int f = 0; f < 9; ++f) {
        const int v = x[n * 9 + f];
        const float4 e = *(const float4*)&aemb[(size_t)(f * 64 + v) * EMB + c0];
        acc.x += e.x; acc.y += e.y; acc.z += e.z; acc.w += e.w;
    }
    *(float4*)&H[(size_t)n * EMB + c0] = acc;
}

// ---------------------------------------------------------------------------
// Edge histogram: src-degree and dst-degree
// ---------------------------------------------------------------------------
__global__ void count_k(const int* __restrict__ srcs, const int* __restrict__ dsts,
                        int* __restrict__ dsrc, int* __restrict__ ddst) {
    int e = blockIdx.x * blockDim.x + threadIdx.x;
    if (e < N_EDGES) {
        atomicAdd(&dsrc[srcs[e]], 1);
        atomicAdd(&ddst[dsts[e]], 1);
    }
}

// ---------------------------------------------------------------------------
// 3-phase exclusive scan of ddst -> rowptr
// ---------------------------------------------------------------------------
__global__ __launch_bounds__(256) void scan1(const int* __restrict__ deg, int* __restrict__ partial) {
    __shared__ int sd[256];
    const int base = blockIdx.x * SCAN_CHUNK + threadIdx.x * 8;
    int s = 0;
#pragma unroll
    for (int i = 0; i < 8; ++i) { int idx = base + i; s += (idx < N_NODES) ? deg[idx] : 0; }
    sd[threadIdx.x] = s; __syncthreads();
    for (int off = 128; off > 0; off >>= 1) {
        if (threadIdx.x < off) sd[threadIdx.x] += sd[threadIdx.x + off];
        __syncthreads();
    }
    if (threadIdx.x == 0) partial[blockIdx.x] = sd[0];
}

__global__ void scan2(int* __restrict__ partial) {
    if (threadIdx.x == 0) {
        int acc = 0;
        for (int i = 0; i < N_CHUNKS; ++i) { int v = partial[i]; partial[i] = acc; acc += v; }
    }
}

__global__ __launch_bounds__(256) void scan3(const int* __restrict__ deg,
                                             const int* __restrict__ partial,
                                             int* __restrict__ rowptr) {
    __shared__ int sd[256];
    const int tid = threadIdx.x;
    const int base = blockIdx.x * SCAN_CHUNK + tid * 8;
    int loc[8]; int s = 0;
#pragma unroll
    for (int i = 0; i < 8; ++i) { int idx = base + i; loc[i] = (idx < N_NODES) ? deg[idx] : 0; s += loc[i]; }
    sd[tid] = s; __syncthreads();
    for (int off = 1; off < 256; off <<= 1) {
        int v = (tid >= off) ? sd[tid - off] : 0;
        __syncthreads();
        sd[tid] += v;
        __syncthreads();
    }
    int excl = partial[blockIdx.x] + sd[tid] - s;
#pragma unroll
    for (int i = 0; i < 8; ++i) {
        int idx = base + i;
        if (idx < N_NODES) { rowptr[idx] = excl; excl += loc[i]; }
    }
    if (blockIdx.x == 0 && tid == 0) rowptr[N_NODES] = N_EDGES;
}

// ---------------------------------------------------------------------------
// Scatter edges into dst-CSR. Record: epk = src | combo<<18 ; enrm = norm.
// ---------------------------------------------------------------------------
__global__ void scatter_k(const int* __restrict__ srcs, const int* __restrict__ dsts,
                          const int* __restrict__ eattr, const int* __restrict__ dsrc,
                          const int* __restrict__ rowptr, int* __restrict__ fill,
                          int* __restrict__ epk, float* __restrict__ enrm) {
    int e = blockIdx.x * blockDim.x + threadIdx.x;
    if (e >= N_EDGES) return;
    const int s = srcs[e];
    const int d = dsts[e];
    const int pos = rowptr[d] + atomicAdd(&fill[d], 1);
    const int c = eattr[e * 3] | (eattr[e * 3 + 1] << 3) | (eattr[e * 3 + 2] << 6);
    epk[pos] = s | (c << 18);
    enrm[pos] = rsqrtf((float)(dsrc[s] + 1) * (float)(dsrc[d] + 1));
}

// ---------------------------------------------------------------------------
// Graph boundaries from sorted batch: gptr[g] = lower_bound(batch, g)
// ---------------------------------------------------------------------------
__global__ void gboundary(const int* __restrict__ batch, int* __restrict__ gptr) {
    int g = blockIdx.x * blockDim.x + threadIdx.x;
    if (g > N_GRAPHS) return;
    if (g == N_GRAPHS) { gptr[g] = N_NODES; return; }
    int lo = 0, hi = N_NODES;
    while (lo < hi) {
        int mid = (lo + hi) >> 1;
        if (batch[mid] < g) lo = mid + 1; else hi = mid;
    }
    gptr[g] = lo;
}

// ---------------------------------------------------------------------------
// Layer GEMM (IN-PLACE over A): XL = act(A) @ W + b ; SELF = relu(XL+root)/(deg+1)
// act(A) = (bnS ? relu(A*bnS + bnT) : A). A/XL alias (block-private rows).
// ---------------------------------------------------------------------------
__global__ __launch_bounds__(256) void gemm_layer(
    const float* A, const float* __restrict__ bnS, const float* __restrict__ bnT,
    const float* __restrict__ W, const float* __restrict__ bias, const float* __restrict__ root,
    const int* __restrict__ dsrc, float* XL, float* SELF) {
    __shared__ float Atile[64][EMB];
    const int tid  = threadIdx.x;
    const size_t rows = (size_t)blockIdx.x * 64;

#pragma unroll
    for (int i = 0; i < 8; ++i) {
        const int v   = tid + i * 256;
        const int row = v >> 5;
        const int c4  = (v & 31) * 4;
        float4 a = *(const float4*)&A[(rows + row) * EMB + c4];
        if (bnS) {
            const float4 s = *(const float4*)&bnS[c4];
            const float4 t = *(const float4*)&bnT[c4];
            a.x = fmaxf(fmaf(a.x, s.x, t.x), 0.f);
            a.y = fmaxf(fmaf(a.y, s.y, t.y), 0.f);
            a.z = fmaxf(fmaf(a.z, s.z, t.z), 0.f);
            a.w = fmaxf(fmaf(a.w, s.w, t.w), 0.f);
        }
        *(float4*)&Atile[row][c4] = a;
    }
    __syncthreads();

    const int tx = tid & 31;
    const int ty = tid >> 5;
    const int c0 = tx * 4;

    float4 acc[8];
#pragma unroll
    for (int r = 0; r < 8; ++r) acc[r] = make_float4(0.f, 0.f, 0.f, 0.f);

#pragma unroll 4
    for (int k = 0; k < EMB; ++k) {
        const float4 w = *(const float4*)&W[(size_t)k * EMB + c0];
#pragma unroll
        for (int r = 0; r < 8; ++r) {
            const float a = Atile[ty * 8 + r][k];
            acc[r].x = fmaf(a, w.x, acc[r].x);
            acc[r].y = fmaf(a, w.y, acc[r].y);
            acc[r].z = fmaf(a, w.z, acc[r].z);
            acc[r].w = fmaf(a, w.w, acc[r].w);
        }
    }

    const float4 b4 = *(const float4*)&bias[c0];
    const float4 r4 = *(const float4*)&root[c0];
#pragma unroll
    for (int r = 0; r < 8; ++r) {
        const size_t R = rows + ty * 8 + r;
        const float dinv = 1.0f / (float)(dsrc[R] + 1);
        float4 o;
        o.x = acc[r].x + b4.x; o.y = acc[r].y + b4.y;
        o.z = acc[r].z + b4.z; o.w = acc[r].w + b4.w;
        *(float4*)&XL[R * EMB + c0] = o;
        float4 s;
        s.x = fmaxf(o.x + r4.x, 0.f) * dinv;
        s.y = fmaxf(o.y + r4.y, 0.f) * dinv;
        s.z = fmaxf(o.z + r4.z, 0.f) * dinv;
        s.w = fmaxf(o.w + r4.w, 0.f) * dinv;
        *(float4*)&SELF[R * EMB + c0] = s;
    }
}

// ---------------------------------------------------------------------------
// Edge aggregation as GATHER (no atomics): half-wave per dst node.
// OUT row pre-seeded with SELF; accumulate incoming messages; write once.
// ---------------------------------------------------------------------------
__global__ __launch_bounds__(256) void edge_gather(
    const int* __restrict__ rowptr, const int* __restrict__ epk,
    const float* __restrict__ enrm, const float* __restrict__ combo,
    const float* __restrict__ XL, float* __restrict__ OUT) {
    const int g = threadIdx.x & 31;
    const int n = blockIdx.x * 8 + (threadIdx.x >> 5);
    if (n >= N_NODES) return;
    const int c0 = g * 4;
    float4 acc = *(const float4*)&OUT[(size_t)n * EMB + c0];   // SELF seed
    const int beg = rowptr[n];
    const int end = rowptr[n + 1];
    for (int i = beg; i < end; ++i) {
        const int  pk = epk[i];
        const float w = enrm[i];
        const int  s  = pk & 0x3FFFF;
        const int  c  = pk >> 18;
        const float4 x  = *(const float4*)&XL[(size_t)s * EMB + c0];
        const float4 cb = *(const float4*)&combo[(size_t)c * EMB + c0];
        acc.x += fmaxf(x.x + cb.x, 0.f) * w;
        acc.y += fmaxf(x.y + cb.y, 0.f) * w;
        acc.z += fmaxf(x.z + cb.z, 0.f) * w;
        acc.w += fmaxf(x.w + cb.w, 0.f) * w;
    }
    *(float4*)&OUT[(size_t)n * EMB + c0] = acc;
}

// ---------------------------------------------------------------------------
// Fused pool+BN+head: one block per graph (batch is sorted -> contiguous).
// hg[ch] = S4[ch]*sum_n H[n][ch] + T4[ch]*count ; out = hg @ HW + hb.
// ---------------------------------------------------------------------------
__global__ __launch_bounds__(128) void pool_head(
    const float* __restrict__ H, const float* __restrict__ S4, const float* __restrict__ T4,
    const int* __restrict__ gptr, const float* __restrict__ HW, const float* __restrict__ hb,
    float* __restrict__ OUT) {
    __shared__ float hr[EMB];
    const int g = blockIdx.x;
    const int t = threadIdx.x;
    const int beg = gptr[g], end = gptr[g + 1];
    float acc = 0.f;
    for (int n = beg; n < end; ++n) acc += H[(size_t)n * EMB + t];
    hr[t] = fmaf(acc, S4[t], T4[t] * (float)(end - beg));
    __syncthreads();
    float o = hb[t];
#pragma unroll 8
    for (int k = 0; k < EMB; ++k) o = fmaf(hr[k], HW[(size_t)k * EMB + t], o);
    OUT[(size_t)g * EMB + t] = o;
}

extern "C" void kernel_launch(void* const* d_in, const int* in_sizes, int n_in,
                              void* d_out, int out_size, void* d_ws, size_t ws_size,
                              hipStream_t stream) {
    const int*   x     = (const int*)d_in[0];
    const int*   ei    = (const int*)d_in[1];    // [2, E]: src then dst
    const int*   ea    = (const int*)d_in[2];    // [E, 3]
    const int*   batch = (const int*)d_in[3];
    const float* aemb  = (const float*)d_in[4];
    const float* bemb  = (const float*)d_in[5];
    const float* W     = (const float*)d_in[6];
    const float* b     = (const float*)d_in[7];
    const float* root  = (const float*)d_in[8];
    const float* bnm   = (const float*)d_in[9];
    const float* bnv   = (const float*)d_in[10];
    const float* bng   = (const float*)d_in[11];
    const float* bnb   = (const float*)d_in[12];
    const float* hW    = (const float*)d_in[13];
    const float* hb    = (const float*)d_in[14];
    float* out = (float*)d_out;

    const size_t NF = (size_t)N_NODES * EMB;
    const size_t n_float = 2 * NF + (size_t)LAYERS * 512 * EMB
                         + 2 * LAYERS * EMB + N_EDGES;
    const size_t n_int   = 3 * (size_t)N_NODES + (N_NODES + 4) + 128
                         + (N_GRAPHS + 4) + N_EDGES;
    const size_t need = (n_float + n_int) * sizeof(float);
    if (ws_size < need) return;  // defensive: fail cleanly, don't fault

    float* f     = (float*)d_ws;
    float* bufA  = f;                          f += NF;
    float* bufB  = f;                          f += NF;
    float* combo = f;                          f += (size_t)LAYERS * 512 * EMB;
    float* S     = f;                          f += LAYERS * EMB;
    float* T     = f;                          f += LAYERS * EMB;
    float* enrm  = f;                          f += N_EDGES;
    int*   ip    = (int*)f;
    int*   dsrc    = ip;                       ip += N_NODES;
    int*   ddst    = ip;                       ip += N_NODES;
    int*   fill    = ip;                       ip += N_NODES;
    int*   rowptr  = ip;                       ip += N_NODES + 4;
    int*   partial = ip;                       ip += 128;
    int*   gptr    = ip;                       ip += N_GRAPHS + 4;
    int*   epk     = ip;                       ip += N_EDGES;

    // zero: dsrc, ddst, fill (contiguous)
    hipMemsetAsync(dsrc, 0, 3 * (size_t)N_NODES * sizeof(int), stream);

    bnprep<<<3, 256, 0, stream>>>(bnm, bnv, bng, bnb, S, T);
    combo_k<<<LAYERS * 512, EMB, 0, stream>>>(bemb, combo);
    encoder<<<N_NODES / 8, 256, 0, stream>>>(x, aemb, bufA);
    count_k<<<(N_EDGES + 255) / 256, 256, 0, stream>>>(ei, ei + N_EDGES, dsrc, ddst);
    scan1<<<N_CHUNKS, 256, 0, stream>>>(ddst, partial);
    scan2<<<1, 64, 0, stream>>>(partial);
    scan3<<<N_CHUNKS, 256, 0, stream>>>(ddst, partial, rowptr);
    scatter_k<<<(N_EDGES + 255) / 256, 256, 0, stream>>>(ei, ei + N_EDGES, ea, dsrc,
                                                         rowptr, fill, epk, enrm);
    gboundary<<<(N_GRAPHS + 256) / 256, 256, 0, stream>>>(batch, gptr);

    // Ping-pong: layer l reads `in`, writes XL in-place over `in`, seeds SELF
    // into `other`; edge_gather accumulates into `other`; next in = other.
    float* in    = bufA;
    float* other = bufB;
    for (int l = 0; l < LAYERS; ++l) {
        gemm_layer<<<N_NODES / 64, 256, 0, stream>>>(
            in, l ? S + (l - 1) * EMB : nullptr, l ? T + (l - 1) * EMB : nullptr,
            W + (size_t)l * EMB * EMB, b + l * EMB, root + l * EMB, dsrc,
            /*XL=*/in, /*SELF=*/other);
        edge_gather<<<N_NODES / 8, 256, 0, stream>>>(
            rowptr, epk, enrm, combo + (size_t)l * 512 * EMB, /*XL=*/in, /*OUT=*/other);
        float* t0 = in; in = other; other = t0;
    }

    pool_head<<<N_GRAPHS, 128, 0, stream>>>(in, S + 4 * EMB, T + 4 * EMB, gptr, hW, hb, out);
}

// Round 5
// 910.146 us; speedup vs baseline: 6.7430x; 1.2553x over previous
//
#include <hip/hip_runtime.h>
#include <hip/hip_bf16.h>

#define N_NODES 200000
#define N_EDGES 600000
#define N_GRAPHS 4000
#define EMB 128
#define LAYERS 5
#define BN_EPS 1e-5f

#define SCAN_CHUNK 2048                   // 256 threads x 8
#define N_CHUNKS ((N_NODES + SCAN_CHUNK - 1) / SCAN_CHUNK)   // 98

typedef __attribute__((ext_vector_type(8))) short short8;   // 8 bf16 (4 VGPRs)
typedef __attribute__((ext_vector_type(4))) float float4v;  // MFMA C/D

// split f32 -> bf16 hi (truncate) + bf16 lo (truncate of residual)
__device__ __forceinline__ void bf16split(float f, unsigned short& hi, unsigned short& lo) {
    unsigned u = __float_as_uint(f);
    hi = (unsigned short)(u >> 16);
    float hf = __uint_as_float((unsigned)hi << 16);
    lo = (unsigned short)(__float_as_uint(f - hf) >> 16);
}

// ---------------------------------------------------------------------------
// BN precompute: S = gamma/sqrt(var+eps), T = beta - mean*S
// ---------------------------------------------------------------------------
__global__ void bnprep(const float* __restrict__ mean, const float* __restrict__ var,
                       const float* __restrict__ gamma, const float* __restrict__ beta,
                       float* __restrict__ S, float* __restrict__ T) {
    int i = blockIdx.x * blockDim.x + threadIdx.x;
    if (i < LAYERS * EMB) {
        float s = gamma[i] / sqrtf(var[i] + BN_EPS);
        S[i] = s;
        T[i] = beta[i] - mean[i] * s;
    }
}

// ---------------------------------------------------------------------------
// W prep: split fp32 W[l][k][n] into bf16 hi/lo, stored in MFMA B-fragment
// swizzled order so a wave's frag load is one coalesced 16B/lane read.
// frag element (k,n): ks=k>>5, ct=n>>4, lane=((k>>3)&3)*16 + (n&15), j=k&7
// off = l*16384 + ((ks*8+ct)*64 + lane)*8 + j
// ---------------------------------------------------------------------------
__global__ void wprep(const float* __restrict__ W, unsigned short* __restrict__ whi,
                      unsigned short* __restrict__ wlo) {
    int idx = blockIdx.x * 256 + threadIdx.x;
    if (idx >= LAYERS * 16384) return;
    const int l = idx >> 14, rem = idx & 16383;
    const int k = rem >> 7, n = rem & 127;
    unsigned short hi, lo;
    bf16split(W[idx], hi, lo);
    const int off = (l << 14) + ((((k >> 5) * 8 + (n >> 4)) * 64
                    + ((k >> 3) & 3) * 16 + (n & 15)) << 3) + (k & 7);
    whi[off] = hi;
    wlo[off] = lo;
}

// ---------------------------------------------------------------------------
// Bond-combo table: combo[l][c][ch] = sum_f bond_emb[l,f,a_f(c)][ch]
// ---------------------------------------------------------------------------
__global__ void combo_k(const float* __restrict__ bemb, float* __restrict__ combo) {
    const int l = blockIdx.x >> 9;
    const int c = blockIdx.x & 511;
    const int a0 = c & 7, a1 = (c >> 3) & 7, a2 = c >> 6;
    const int t = threadIdx.x;
    combo[(size_t)blockIdx.x * EMB + t] =
        bemb[(size_t)((l * 3 + 0) * 8 + a0) * EMB + t] +
        bemb[(size_t)((l * 3 + 1) * 8 + a1) * EMB + t] +
        bemb[(size_t)((l * 3 + 2) * 8 + a2) * EMB + t];
}

// ---------------------------------------------------------------------------
// Atom encoder
// ---------------------------------------------------------------------------
__global__ __launch_bounds__(256) void encoder(const int* __restrict__ x,
                                               const float* __restrict__ aemb,
                                               float* __restrict__ H) {
    const int g  = threadIdx.x & 31;
    const int n  = blockIdx.x * 8 + (threadIdx.x >> 5);
    if (n >= N_NODES) return;
    const int c0 = g * 4;
    float4 acc = make_float4(0.f, 0.f, 0.f, 0.f);
#pragma unroll
    for (int f = 0; f < 9; ++f) {
        const int v = x[n * 9 + f];
        const float4 e = *(const float4*)&aemb[(size_t)(f * 64 + v) * EMB + c0];
        acc.x += e.x; acc.y += e.y; acc.z += e.z; acc.w += e.w;
    }
    *(float4*)&H[(size_t)n * EMB + c0] = acc;
}

// ---------------------------------------------------------------------------
// Edge histogram: src-degree and dst-degree
// ---------------------------------------------------------------------------
__global__ void count_k(const int* __restrict__ srcs, const int* __restrict__ dsts,
                        int* __restrict__ dsrc, int* __restrict__ ddst) {
    int e = blockIdx.x * blockDim.x + threadIdx.x;
    if (e < N_EDGES) {
        atomicAdd(&dsrc[srcs[e]], 1);
        atomicAdd(&ddst[dsts[e]], 1);
    }
}

// ---------------------------------------------------------------------------
// 3-phase exclusive scan of ddst -> rowptr
// ---------------------------------------------------------------------------
__global__ __launch_bounds__(256) void scan1(const int* __restrict__ deg, int* __restrict__ partial) {
    __shared__ int sd[256];
    const int base = blockIdx.x * SCAN_CHUNK + threadIdx.x * 8;
    int s = 0;
#pragma unroll
    for (int i = 0; i < 8; ++i) { int idx = base + i; s += (idx < N_NODES) ? deg[idx] : 0; }
    sd[threadIdx.x] = s; __syncthreads();
    for (int off = 128; off > 0; off >>= 1) {
        if (threadIdx.x < off) sd[threadIdx.x] += sd[threadIdx.x + off];
        __syncthreads();
    }
    if (threadIdx.x == 0) partial[blockIdx.x] = sd[0];
}

__global__ void scan2(int* __restrict__ partial) {
    if (threadIdx.x == 0) {
        int acc = 0;
        for (int i = 0; i < N_CHUNKS; ++i) { int v = partial[i]; partial[i] = acc; acc += v; }
    }
}

__global__ __launch_bounds__(256) void scan3(const int* __restrict__ deg,
                                             const int* __restrict__ partial,
                                             int* __restrict__ rowptr) {
    __shared__ int sd[256];
    const int tid = threadIdx.x;
    const int base = blockIdx.x * SCAN_CHUNK + tid * 8;
    int loc[8]; int s = 0;
#pragma unroll
    for (int i = 0; i < 8; ++i) { int idx = base + i; loc[i] = (idx < N_NODES) ? deg[idx] : 0; s += loc[i]; }
    sd[tid] = s; __syncthreads();
    for (int off = 1; off < 256; off <<= 1) {
        int v = (tid >= off) ? sd[tid - off] : 0;
        __syncthreads();
        sd[tid] += v;
        __syncthreads();
    }
    int excl = partial[blockIdx.x] + sd[tid] - s;
#pragma unroll
    for (int i = 0; i < 8; ++i) {
        int idx = base + i;
        if (idx < N_NODES) { rowptr[idx] = excl; excl += loc[i]; }
    }
    if (blockIdx.x == 0 && tid == 0) rowptr[N_NODES] = N_EDGES;
}

// ---------------------------------------------------------------------------
// Scatter edges into dst-CSR. Record: epk = src | combo<<18 ; enrm = norm.
// ---------------------------------------------------------------------------
__global__ void scatter_k(const int* __restrict__ srcs, const int* __restrict__ dsts,
                          const int* __restrict__ eattr, const int* __restrict__ dsrc,
                          const int* __restrict__ rowptr, int* __restrict__ fill,
                          int* __restrict__ epk, float* __restrict__ enrm) {
    int e = blockIdx.x * blockDim.x + threadIdx.x;
    if (e >= N_EDGES) return;
    const int s = srcs[e];
    const int d = dsts[e];
    const int pos = rowptr[d] + atomicAdd(&fill[d], 1);
    const int c = eattr[e * 3] | (eattr[e * 3 + 1] << 3) | (eattr[e * 3 + 2] << 6);
    epk[pos] = s | (c << 18);
    enrm[pos] = rsqrtf((float)(dsrc[s] + 1) * (float)(dsrc[d] + 1));
}

// ---------------------------------------------------------------------------
// Graph boundaries from sorted batch
// ---------------------------------------------------------------------------
__global__ void gboundary(const int* __restrict__ batch, int* __restrict__ gptr) {
    int g = blockIdx.x * blockDim.x + threadIdx.x;
    if (g > N_GRAPHS) return;
    if (g == N_GRAPHS) { gptr[g] = N_NODES; return; }
    int lo = 0, hi = N_NODES;
    while (lo < hi) {
        int mid = (lo + hi) >> 1;
        if (batch[mid] < g) lo = mid + 1; else hi = mid;
    }
    gptr[g] = lo;
}

// ---------------------------------------------------------------------------
// Layer GEMM via split-bf16 MFMA (IN-PLACE over A): XL = act(A) @ W + b
// act(A) = (bnS ? relu(A*bnS + bnT) : A); A split to bf16 hi/lo in LDS.
// D = Ah*Wh + Ah*Wl + Al*Wh (fp32 acc) -> ~fp32 precision.
// Block: 64 rows x 128 cols, 4 waves; wave w owns rows [w*16, w*16+16),
// 8 col-tiles of 16. mfma_f32_16x16x32_bf16:
//   A-frag: A[m=lane&15][k = (lane>>4)*8 + j]   (8 bf16, contiguous k)
//   B-frag: B[k = (lane>>4)*8 + j][n=lane&15]   (pre-swizzled by wprep)
//   C/D   : col=lane&15, row=(lane>>4)*4 + reg
// ---------------------------------------------------------------------------
__global__ __launch_bounds__(256) void gemm_layer(
    const float* A, const float* __restrict__ bnS, const float* __restrict__ bnT,
    const unsigned short* __restrict__ whi, const unsigned short* __restrict__ wlo,
    const float* __restrict__ bias, float* XL) {
    __shared__ unsigned short Ah[64][136];   // +8 pad: frag reads ~2-way conflicts
    __shared__ unsigned short Al[64][136];
    const int tid  = threadIdx.x;
    const size_t rows = (size_t)blockIdx.x * 64;

    // stage act(A) split into bf16 hi/lo
#pragma unroll
    for (int i = 0; i < 8; ++i) {
        const int v   = tid + i * 256;
        const int row = v >> 5;
        const int c4  = (v & 31) * 4;
        float4 a = *(const float4*)&A[(rows + row) * EMB + c4];
        if (bnS) {
            const float4 s = *(const float4*)&bnS[c4];
            const float4 t = *(const float4*)&bnT[c4];
            a.x = fmaxf(fmaf(a.x, s.x, t.x), 0.f);
            a.y = fmaxf(fmaf(a.y, s.y, t.y), 0.f);
            a.z = fmaxf(fmaf(a.z, s.z, t.z), 0.f);
            a.w = fmaxf(fmaf(a.w, s.w, t.w), 0.f);
        }
        ushort4 hi, lo;
        bf16split(a.x, hi.x, lo.x);
        bf16split(a.y, hi.y, lo.y);
        bf16split(a.z, hi.z, lo.z);
        bf16split(a.w, hi.w, lo.w);
        *(ushort4*)&Ah[row][c4] = hi;
        *(ushort4*)&Al[row][c4] = lo;
    }
    __syncthreads();

    const int wave = tid >> 6;
    const int lane = tid & 63;
    const int quad = lane >> 4;
    const int n15  = lane & 15;
    const int wrow = wave * 16 + n15;       // A-frag m index (lane&15)

    float4v acc[8];
#pragma unroll
    for (int ct = 0; ct < 8; ++ct) acc[ct] = (float4v)(0.f);

    const short8* __restrict__ Bh = (const short8*)whi;
    const short8* __restrict__ Bl = (const short8*)wlo;

#pragma unroll
    for (int ks = 0; ks < 4; ++ks) {
        const int k0 = ks * 32 + quad * 8;
        const short8 ah = *(const short8*)&Ah[wrow][k0];
        const short8 al = *(const short8*)&Al[wrow][k0];
#pragma unroll
        for (int ct = 0; ct < 8; ++ct) {
            const short8 bh = Bh[(ks * 8 + ct) * 64 + lane];
            const short8 bl = Bl[(ks * 8 + ct) * 64 + lane];
            acc[ct] = __builtin_amdgcn_mfma_f32_16x16x32_bf16(ah, bh, acc[ct], 0, 0, 0);
            acc[ct] = __builtin_amdgcn_mfma_f32_16x16x32_bf16(ah, bl, acc[ct], 0, 0, 0);
            acc[ct] = __builtin_amdgcn_mfma_f32_16x16x32_bf16(al, bh, acc[ct], 0, 0, 0);
        }
    }

    const size_t rowBase = rows + wave * 16 + quad * 4;
#pragma unroll
    for (int ct = 0; ct < 8; ++ct) {
        const int col = ct * 16 + n15;
        const float bc = bias[col];
#pragma unroll
        for (int r = 0; r < 4; ++r)
            XL[(rowBase + r) * EMB + col] = acc[ct][r] + bc;
    }
}

// ---------------------------------------------------------------------------
// Edge aggregation as GATHER (no atomics): half-wave per dst node.
// Seed = relu(XL[n]+root)/(dsrc[n]+1) computed in-kernel (no SELF buffer).
// ---------------------------------------------------------------------------
__global__ __launch_bounds__(256) void edge_gather(
    const int* __restrict__ rowptr, const int* __restrict__ epk,
    const float* __restrict__ enrm, const float* __restrict__ combo,
    const float* __restrict__ root, const int* __restrict__ dsrc,
    const float* __restrict__ XL, float* __restrict__ OUT) {
    const int g = threadIdx.x & 31;
    const int n = blockIdx.x * 8 + (threadIdx.x >> 5);
    if (n >= N_NODES) return;
    const int c0 = g * 4;
    const float dinv = 1.0f / (float)(dsrc[n] + 1);
    const float4 r4 = *(const float4*)&root[c0];
    const float4 xn = *(const float4*)&XL[(size_t)n * EMB + c0];
    float4 acc;
    acc.x = fmaxf(xn.x + r4.x, 0.f) * dinv;
    acc.y = fmaxf(xn.y + r4.y, 0.f) * dinv;
    acc.z = fmaxf(xn.z + r4.z, 0.f) * dinv;
    acc.w = fmaxf(xn.w + r4.w, 0.f) * dinv;
    const int beg = rowptr[n];
    const int end = rowptr[n + 1];
    for (int i = beg; i < end; ++i) {
        const int  pk = epk[i];
        const float w = enrm[i];
        const int  s  = pk & 0x3FFFF;
        const int  c  = pk >> 18;
        const float4 x  = *(const float4*)&XL[(size_t)s * EMB + c0];
        const float4 cb = *(const float4*)&combo[(size_t)c * EMB + c0];
        acc.x += fmaxf(x.x + cb.x, 0.f) * w;
        acc.y += fmaxf(x.y + cb.y, 0.f) * w;
        acc.z += fmaxf(x.z + cb.z, 0.f) * w;
        acc.w += fmaxf(x.w + cb.w, 0.f) * w;
    }
    *(float4*)&OUT[(size_t)n * EMB + c0] = acc;
}

// ---------------------------------------------------------------------------
// Fused pool+BN+head: one block per graph (batch sorted -> contiguous).
// ---------------------------------------------------------------------------
__global__ __launch_bounds__(128) void pool_head(
    const float* __restrict__ H, const float* __restrict__ S4, const float* __restrict__ T4,
    const int* __restrict__ gptr, const float* __restrict__ HW, const float* __restrict__ hb,
    float* __restrict__ OUT) {
    __shared__ float hr[EMB];
    const int g = blockIdx.x;
    const int t = threadIdx.x;
    const int beg = gptr[g], end = gptr[g + 1];
    float acc = 0.f;
    for (int n = beg; n < end; ++n) acc += H[(size_t)n * EMB + t];
    hr[t] = fmaf(acc, S4[t], T4[t] * (float)(end - beg));
    __syncthreads();
    float o = hb[t];
#pragma unroll 8
    for (int k = 0; k < EMB; ++k) o = fmaf(hr[k], HW[(size_t)k * EMB + t], o);
    OUT[(size_t)g * EMB + t] = o;
}

extern "C" void kernel_launch(void* const* d_in, const int* in_sizes, int n_in,
                              void* d_out, int out_size, void* d_ws, size_t ws_size,
                              hipStream_t stream) {
    const int*   x     = (const int*)d_in[0];
    const int*   ei    = (const int*)d_in[1];    // [2, E]: src then dst
    const int*   ea    = (const int*)d_in[2];    // [E, 3]
    const int*   batch = (const int*)d_in[3];
    const float* aemb  = (const float*)d_in[4];
    const float* bemb  = (const float*)d_in[5];
    const float* W     = (const float*)d_in[6];
    const float* b     = (const float*)d_in[7];
    const float* root  = (const float*)d_in[8];
    const float* bnm   = (const float*)d_in[9];
    const float* bnv   = (const float*)d_in[10];
    const float* bng   = (const float*)d_in[11];
    const float* bnb   = (const float*)d_in[12];
    const float* hW    = (const float*)d_in[13];
    const float* hb    = (const float*)d_in[14];
    float* out = (float*)d_out;

    const size_t NF = (size_t)N_NODES * EMB;
    const size_t n_float = 2 * NF + (size_t)LAYERS * 512 * EMB
                         + 2 * LAYERS * EMB + N_EDGES
                         + 2 * ((size_t)LAYERS * 16384 / 2 + 64);   // whi/wlo as ushort
    const size_t n_int   = 3 * (size_t)N_NODES + (N_NODES + 4) + 128
                         + (N_GRAPHS + 4) + N_EDGES;
    const size_t need = (n_float + n_int) * sizeof(float);
    if (ws_size < need) return;  // defensive: fail cleanly, don't fault

    float* f     = (float*)d_ws;
    float* bufA  = f;                          f += NF;
    float* bufB  = f;                          f += NF;
    float* combo = f;                          f += (size_t)LAYERS * 512 * EMB;
    float* S     = f;                          f += LAYERS * EMB;
    float* T     = f;                          f += LAYERS * EMB;
    float* enrm  = f;                          f += N_EDGES;
    unsigned short* whi = (unsigned short*)f;  f += (size_t)LAYERS * 16384 / 2 + 64;
    unsigned short* wlo = (unsigned short*)f;  f += (size_t)LAYERS * 16384 / 2 + 64;
    int*   ip    = (int*)f;
    int*   dsrc    = ip;                       ip += N_NODES;
    int*   ddst    = ip;                       ip += N_NODES;
    int*   fill    = ip;                       ip += N_NODES;
    int*   rowptr  = ip;                       ip += N_NODES + 4;
    int*   partial = ip;                       ip += 128;
    int*   gptr    = ip;                       ip += N_GRAPHS + 4;
    int*   epk     = ip;                       ip += N_EDGES;

    // zero: dsrc, ddst, fill (contiguous)
    hipMemsetAsync(dsrc, 0, 3 * (size_t)N_NODES * sizeof(int), stream);

    bnprep<<<3, 256, 0, stream>>>(bnm, bnv, bng, bnb, S, T);
    wprep<<<(LAYERS * 16384 + 255) / 256, 256, 0, stream>>>(W, whi, wlo);
    combo_k<<<LAYERS * 512, EMB, 0, stream>>>(bemb, combo);
    encoder<<<N_NODES / 8, 256, 0, stream>>>(x, aemb, bufA);
    count_k<<<(N_EDGES + 255) / 256, 256, 0, stream>>>(ei, ei + N_EDGES, dsrc, ddst);
    scan1<<<N_CHUNKS, 256, 0, stream>>>(ddst, partial);
    scan2<<<1, 64, 0, stream>>>(partial);
    scan3<<<N_CHUNKS, 256, 0, stream>>>(ddst, partial, rowptr);
    scatter_k<<<(N_EDGES + 255) / 256, 256, 0, stream>>>(ei, ei + N_EDGES, ea, dsrc,
                                                         rowptr, fill, epk, enrm);
    gboundary<<<(N_GRAPHS + 256) / 256, 256, 0, stream>>>(batch, gptr);

    // Ping-pong: layer l reads `in`, writes XL in-place over `in`;
    // edge_gather computes self-term from XL and writes `other`; in = other.
    float* in    = bufA;
    float* other = bufB;
    for (int l = 0; l < LAYERS; ++l) {
        gemm_layer<<<N_NODES / 64, 256, 0, stream>>>(
            in, l ? S + (l - 1) * EMB : nullptr, l ? T + (l - 1) * EMB : nullptr,
            whi + (size_t)l * 16384, wlo + (size_t)l * 16384,
            b + l * EMB, /*XL=*/in);
        edge_gather<<<N_NODES / 8, 256, 0, stream>>>(
            rowptr, epk, enrm, combo + (size_t)l * 512 * EMB,
            root + l * EMB, dsrc, /*XL=*/in, /*OUT=*/other);
        float* t0 = in; in = other; other = t0;
    }

    pool_head<<<N_GRAPHS, 128, 0, stream>>>(in, S + 4 * EMB, T + 4 * EMB, gptr, hW, hb, out);
}

// Round 6
// 751.807 us; speedup vs baseline: 8.1632x; 1.2106x over previous
//
#include <hip/hip_runtime.h>
#include <hip/hip_bf16.h>

#define N_NODES 200000
#define N_EDGES 600000
#define N_GRAPHS 4000
#define EMB 128
#define LAYERS 5
#define BN_EPS 1e-5f

#define SCAN_CHUNK 2048                   // 256 threads x 8
#define N_CHUNKS ((N_NODES + SCAN_CHUNK - 1) / SCAN_CHUNK)   // 98

typedef __attribute__((ext_vector_type(8))) short short8;   // 8 bf16 (4 VGPRs)
typedef __attribute__((ext_vector_type(4))) float float4v;  // MFMA C/D

// split f32 -> bf16 hi (truncate) + bf16 lo (truncate of residual)
__device__ __forceinline__ void bf16split(float f, unsigned short& hi, unsigned short& lo) {
    unsigned u = __float_as_uint(f);
    hi = (unsigned short)(u >> 16);
    float hf = __uint_as_float((unsigned)hi << 16);
    lo = (unsigned short)(__float_as_uint(f - hf) >> 16);
}

// ---------------------------------------------------------------------------
// BN precompute: S = gamma/sqrt(var+eps), T = beta - mean*S
// ---------------------------------------------------------------------------
__global__ void bnprep(const float* __restrict__ mean, const float* __restrict__ var,
                       const float* __restrict__ gamma, const float* __restrict__ beta,
                       float* __restrict__ S, float* __restrict__ T) {
    int i = blockIdx.x * blockDim.x + threadIdx.x;
    if (i < LAYERS * EMB) {
        float s = gamma[i] / sqrtf(var[i] + BN_EPS);
        S[i] = s;
        T[i] = beta[i] - mean[i] * s;
    }
}

// ---------------------------------------------------------------------------
// W prep: split fp32 W[l][k][n] into bf16 hi/lo in MFMA B-fragment swizzled
// order: off = l*16384 + ((ks*8+ct)*64 + lane)*8 + j
//   ks=k>>5, ct=n>>4, lane=((k>>3)&3)*16+(n&15), j=k&7
// ---------------------------------------------------------------------------
__global__ void wprep(const float* __restrict__ W, unsigned short* __restrict__ whi,
                      unsigned short* __restrict__ wlo) {
    int idx = blockIdx.x * 256 + threadIdx.x;
    if (idx >= LAYERS * 16384) return;
    const int l = idx >> 14, rem = idx & 16383;
    const int k = rem >> 7, n = rem & 127;
    unsigned short hi, lo;
    bf16split(W[idx], hi, lo);
    const int off = (l << 14) + ((((k >> 5) * 8 + (n >> 4)) * 64
                    + ((k >> 3) & 3) * 16 + (n & 15)) << 3) + (k & 7);
    whi[off] = hi;
    wlo[off] = lo;
}

// ---------------------------------------------------------------------------
// Bond-combo table: combo[l][c][ch] = sum_f bond_emb[l,f,a_f(c)][ch]
// ---------------------------------------------------------------------------
__global__ void combo_k(const float* __restrict__ bemb, float* __restrict__ combo) {
    const int l = blockIdx.x >> 9;
    const int c = blockIdx.x & 511;
    const int a0 = c & 7, a1 = (c >> 3) & 7, a2 = c >> 6;
    const int t = threadIdx.x;
    combo[(size_t)blockIdx.x * EMB + t] =
        bemb[(size_t)((l * 3 + 0) * 8 + a0) * EMB + t] +
        bemb[(size_t)((l * 3 + 1) * 8 + a1) * EMB + t] +
        bemb[(size_t)((l * 3 + 2) * 8 + a2) * EMB + t];
}

// ---------------------------------------------------------------------------
// Edge histogram: src-degree and dst-degree
// ---------------------------------------------------------------------------
__global__ void count_k(const int* __restrict__ srcs, const int* __restrict__ dsts,
                        int* __restrict__ dsrc, int* __restrict__ ddst) {
    int e = blockIdx.x * blockDim.x + threadIdx.x;
    if (e < N_EDGES) {
        atomicAdd(&dsrc[srcs[e]], 1);
        atomicAdd(&ddst[dsts[e]], 1);
    }
}

// ---------------------------------------------------------------------------
// 3-phase exclusive scan of ddst -> rowptr
// ---------------------------------------------------------------------------
__global__ __launch_bounds__(256) void scan1(const int* __restrict__ deg, int* __restrict__ partial) {
    __shared__ int sd[256];
    const int base = blockIdx.x * SCAN_CHUNK + threadIdx.x * 8;
    int s = 0;
#pragma unroll
    for (int i = 0; i < 8; ++i) { int idx = base + i; s += (idx < N_NODES) ? deg[idx] : 0; }
    sd[threadIdx.x] = s; __syncthreads();
    for (int off = 128; off > 0; off >>= 1) {
        if (threadIdx.x < off) sd[threadIdx.x] += sd[threadIdx.x + off];
        __syncthreads();
    }
    if (threadIdx.x == 0) partial[blockIdx.x] = sd[0];
}

__global__ void scan2(int* __restrict__ partial) {
    if (threadIdx.x == 0) {
        int acc = 0;
        for (int i = 0; i < N_CHUNKS; ++i) { int v = partial[i]; partial[i] = acc; acc += v; }
    }
}

__global__ __launch_bounds__(256) void scan3(const int* __restrict__ deg,
                                             const int* __restrict__ partial,
                                             int* __restrict__ rowptr) {
    __shared__ int sd[256];
    const int tid = threadIdx.x;
    const int base = blockIdx.x * SCAN_CHUNK + tid * 8;
    int loc[8]; int s = 0;
#pragma unroll
    for (int i = 0; i < 8; ++i) { int idx = base + i; loc[i] = (idx < N_NODES) ? deg[idx] : 0; s += loc[i]; }
    sd[tid] = s; __syncthreads();
    for (int off = 1; off < 256; off <<= 1) {
        int v = (tid >= off) ? sd[tid - off] : 0;
        __syncthreads();
        sd[tid] += v;
        __syncthreads();
    }
    int excl = partial[blockIdx.x] + sd[tid] - s;
#pragma unroll
    for (int i = 0; i < 8; ++i) {
        int idx = base + i;
        if (idx < N_NODES) { rowptr[idx] = excl; excl += loc[i]; }
    }
    if (blockIdx.x == 0 && tid == 0) rowptr[N_NODES] = N_EDGES;
}

// ---------------------------------------------------------------------------
// Scatter edges into dst-CSR. Record: epk = src | combo<<18 ; enrm = norm.
// ---------------------------------------------------------------------------
__global__ void scatter_k(const int* __restrict__ srcs, const int* __restrict__ dsts,
                          const int* __restrict__ eattr, const int* __restrict__ dsrc,
                          const int* __restrict__ rowptr, int* __restrict__ fill,
                          int* __restrict__ epk, float* __restrict__ enrm) {
    int e = blockIdx.x * blockDim.x + threadIdx.x;
    if (e >= N_EDGES) return;
    const int s = srcs[e];
    const int d = dsts[e];
    const int pos = rowptr[d] + atomicAdd(&fill[d], 1);
    const int c = eattr[e * 3] | (eattr[e * 3 + 1] << 3) | (eattr[e * 3 + 2] << 6);
    epk[pos] = s | (c << 18);
    enrm[pos] = rsqrtf((float)(dsrc[s] + 1) * (float)(dsrc[d] + 1));
}

// ---------------------------------------------------------------------------
// MFMA tile: 32 rows x 128 cols from bf16 hi/lo LDS tiles; wave w owns
// rows (w&1)*16..+16, cols (w>>1)*64..+64. 16x16x32 bf16, 3-term split.
// ---------------------------------------------------------------------------
__device__ __forceinline__ void mfma_tile(
    const unsigned short (*Ah)[136], const unsigned short (*Al)[136],
    const short8* __restrict__ Bh, const short8* __restrict__ Bl,
    const float* __restrict__ bias, float* __restrict__ XLout,
    size_t rows, int tid) {
    const int wave = tid >> 6;
    const int lane = tid & 63;
    const int quad = lane >> 4;
    const int n15  = lane & 15;
    const int wrow = (wave & 1) * 16 + n15;
    const int cbase = (wave >> 1) * 4;      // col-tile base (x16)

    float4v acc[4];
#pragma unroll
    for (int ct = 0; ct < 4; ++ct) acc[ct] = (float4v)(0.f);

#pragma unroll
    for (int ks = 0; ks < 4; ++ks) {
        const int k0 = ks * 32 + quad * 8;
        const short8 ah = *(const short8*)&Ah[wrow][k0];
        const short8 al = *(const short8*)&Al[wrow][k0];
#pragma unroll
        for (int ct = 0; ct < 4; ++ct) {
            const int ctg = cbase + ct;
            const short8 bh = Bh[(ks * 8 + ctg) * 64 + lane];
            const short8 bl = Bl[(ks * 8 + ctg) * 64 + lane];
            acc[ct] = __builtin_amdgcn_mfma_f32_16x16x32_bf16(ah, bh, acc[ct], 0, 0, 0);
            acc[ct] = __builtin_amdgcn_mfma_f32_16x16x32_bf16(ah, bl, acc[ct], 0, 0, 0);
            acc[ct] = __builtin_amdgcn_mfma_f32_16x16x32_bf16(al, bh, acc[ct], 0, 0, 0);
        }
    }

    const size_t rowBase = rows + (wave & 1) * 16 + quad * 4;
#pragma unroll
    for (int ct = 0; ct < 4; ++ct) {
        const int col = (cbase + ct) * 16 + n15;
        const float bc = bias[col];
#pragma unroll
        for (int r = 0; r < 4; ++r)
            XLout[(rowBase + r) * EMB + col] = acc[ct][r] + bc;
    }
}

// ---------------------------------------------------------------------------
// Fused atom-encoder + GEMM layer 0: h0 rows -> LDS (bf16 split) -> XL0
// ---------------------------------------------------------------------------
__global__ __launch_bounds__(256) void enc_gemm(
    const int* __restrict__ x, const float* __restrict__ aemb,
    const unsigned short* __restrict__ whi, const unsigned short* __restrict__ wlo,
    const float* __restrict__ bias, float* __restrict__ XL) {
    __shared__ unsigned short Ah[32][136];
    __shared__ unsigned short Al[32][136];
    const int tid = threadIdx.x;
    const int g = tid & 31, hw = tid >> 5;
    const int c0 = g * 4;
    const size_t rows = (size_t)blockIdx.x * 32;

#pragma unroll
    for (int i = 0; i < 4; ++i) {
        const int row = hw * 4 + i;
        const size_t n = rows + row;
        float4 acc = make_float4(0.f, 0.f, 0.f, 0.f);
#pragma unroll
        for (int ff = 0; ff < 9; ++ff) {
            const int v = x[n * 9 + ff];
            const float4 e = *(const float4*)&aemb[(size_t)(ff * 64 + v) * EMB + c0];
            acc.x += e.x; acc.y += e.y; acc.z += e.z; acc.w += e.w;
        }
        ushort4 hi, lo;
        bf16split(acc.x, hi.x, lo.x);
        bf16split(acc.y, hi.y, lo.y);
        bf16split(acc.z, hi.z, lo.z);
        bf16split(acc.w, hi.w, lo.w);
        *(ushort4*)&Ah[row][c0] = hi;
        *(ushort4*)&Al[row][c0] = lo;
    }
    __syncthreads();
    mfma_tile(Ah, Al, (const short8*)whi, (const short8*)wlo, bias, XL, rows, tid);
}

// ---------------------------------------------------------------------------
// Fused gather(layer l) + BN_l + ReLU + GEMM(layer l+1), l = 0..3.
// Half-wave gathers 4 rows (seed + CSR edges), splits to LDS; MFMA phase.
// h never touches HBM.
// ---------------------------------------------------------------------------
__global__ __launch_bounds__(256) void gather_gemm(
    const int* __restrict__ rowptr, const int* __restrict__ epk,
    const float* __restrict__ enrm, const float* __restrict__ combo,
    const float* __restrict__ root, const int* __restrict__ dsrc,
    const float* __restrict__ bnS, const float* __restrict__ bnT,
    const unsigned short* __restrict__ whi, const unsigned short* __restrict__ wlo,
    const float* __restrict__ bias,
    const float* __restrict__ XLin, float* __restrict__ XLout) {
    __shared__ unsigned short Ah[32][136];
    __shared__ unsigned short Al[32][136];
    const int tid = threadIdx.x;
    const int g = tid & 31, hw = tid >> 5;
    const int c0 = g * 4;
    const size_t rows = (size_t)blockIdx.x * 32;

    const float4 r4 = *(const float4*)&root[c0];
    const float4 s4 = *(const float4*)&bnS[c0];
    const float4 t4 = *(const float4*)&bnT[c0];

#pragma unroll
    for (int i = 0; i < 4; ++i) {
        const int row = hw * 4 + i;
        const size_t n = rows + row;
        const float dinv = 1.0f / (float)(dsrc[n] + 1);
        const float4 xn = *(const float4*)&XLin[n * EMB + c0];
        float4 acc;
        acc.x = fmaxf(xn.x + r4.x, 0.f) * dinv;
        acc.y = fmaxf(xn.y + r4.y, 0.f) * dinv;
        acc.z = fmaxf(xn.z + r4.z, 0.f) * dinv;
        acc.w = fmaxf(xn.w + r4.w, 0.f) * dinv;
        const int beg = rowptr[n], end = rowptr[n + 1];
        int pk = 0; float wgt = 0.f;
        if (beg < end) { pk = epk[beg]; wgt = enrm[beg]; }
        for (int e = beg; e < end; ++e) {
            const int pk_c = pk; const float w_c = wgt;
            if (e + 1 < end) { pk = epk[e + 1]; wgt = enrm[e + 1]; }   // prefetch
            const int s = pk_c & 0x3FFFF;
            const int c = pk_c >> 18;
            const float4 xv = *(const float4*)&XLin[(size_t)s * EMB + c0];
            const float4 cb = *(const float4*)&combo[(size_t)c * EMB + c0];
            acc.x += fmaxf(xv.x + cb.x, 0.f) * w_c;
            acc.y += fmaxf(xv.y + cb.y, 0.f) * w_c;
            acc.z += fmaxf(xv.z + cb.z, 0.f) * w_c;
            acc.w += fmaxf(xv.w + cb.w, 0.f) * w_c;
        }
        // BN + ReLU (next-layer activation), split to LDS
        float4 h;
        h.x = fmaxf(fmaf(acc.x, s4.x, t4.x), 0.f);
        h.y = fmaxf(fmaf(acc.y, s4.y, t4.y), 0.f);
        h.z = fmaxf(fmaf(acc.z, s4.z, t4.z), 0.f);
        h.w = fmaxf(fmaf(acc.w, s4.w, t4.w), 0.f);
        ushort4 hi, lo;
        bf16split(h.x, hi.x, lo.x);
        bf16split(h.y, hi.y, lo.y);
        bf16split(h.z, hi.z, lo.z);
        bf16split(h.w, hi.w, lo.w);
        *(ushort4*)&Ah[row][c0] = hi;
        *(ushort4*)&Al[row][c0] = lo;
    }
    __syncthreads();
    mfma_tile(Ah, Al, (const short8*)whi, (const short8*)wlo, bias, XLout, rows, tid);
}

// ---------------------------------------------------------------------------
// Fused final gather(layer 4) + BN4 + segmented pool over sorted batch.
// Half-wave walks 8 sequential nodes, keeps per-graph partial in registers,
// flushes to hg at graph boundaries (few atomics, no h materialization).
// ---------------------------------------------------------------------------
__global__ __launch_bounds__(256) void gather_pool(
    const int* __restrict__ rowptr, const int* __restrict__ epk,
    const float* __restrict__ enrm, const float* __restrict__ combo,
    const float* __restrict__ root, const int* __restrict__ dsrc,
    const float* __restrict__ S4, const float* __restrict__ T4,
    const int* __restrict__ batch, const float* __restrict__ XLin,
    float* __restrict__ hg) {
    const int g = threadIdx.x & 31, hw = threadIdx.x >> 5;
    const int c0 = g * 4;
    const size_t base = (size_t)blockIdx.x * 64 + hw * 8;

    const float4 r4 = *(const float4*)&root[c0];
    const float4 s4 = *(const float4*)&S4[c0];
    const float4 t4 = *(const float4*)&T4[c0];

    float4 seg = make_float4(0.f, 0.f, 0.f, 0.f);
    int cur = batch[base];
#pragma unroll
    for (int i = 0; i < 8; ++i) {
        const size_t n = base + i;
        const int bg = batch[n];
        if (bg != cur) {
            float* o = &hg[(size_t)cur * EMB + c0];
            unsafeAtomicAdd(o + 0, seg.x);
            unsafeAtomicAdd(o + 1, seg.y);
            unsafeAtomicAdd(o + 2, seg.z);
            unsafeAtomicAdd(o + 3, seg.w);
            seg = make_float4(0.f, 0.f, 0.f, 0.f);
            cur = bg;
        }
        const float dinv = 1.0f / (float)(dsrc[n] + 1);
        const float4 xn = *(const float4*)&XLin[n * EMB + c0];
        float4 acc;
        acc.x = fmaxf(xn.x + r4.x, 0.f) * dinv;
        acc.y = fmaxf(xn.y + r4.y, 0.f) * dinv;
        acc.z = fmaxf(xn.z + r4.z, 0.f) * dinv;
        acc.w = fmaxf(xn.w + r4.w, 0.f) * dinv;
        const int beg = rowptr[n], end = rowptr[n + 1];
        int pk = 0; float wgt = 0.f;
        if (beg < end) { pk = epk[beg]; wgt = enrm[beg]; }
        for (int e = beg; e < end; ++e) {
            const int pk_c = pk; const float w_c = wgt;
            if (e + 1 < end) { pk = epk[e + 1]; wgt = enrm[e + 1]; }
            const int s = pk_c & 0x3FFFF;
            const int c = pk_c >> 18;
            const float4 xv = *(const float4*)&XLin[(size_t)s * EMB + c0];
            const float4 cb = *(const float4*)&combo[(size_t)c * EMB + c0];
            acc.x += fmaxf(xv.x + cb.x, 0.f) * w_c;
            acc.y += fmaxf(xv.y + cb.y, 0.f) * w_c;
            acc.z += fmaxf(xv.z + cb.z, 0.f) * w_c;
            acc.w += fmaxf(xv.w + cb.w, 0.f) * w_c;
        }
        // BN4 (no relu), accumulate into graph partial
        seg.x += fmaf(acc.x, s4.x, t4.x);
        seg.y += fmaf(acc.y, s4.y, t4.y);
        seg.z += fmaf(acc.z, s4.z, t4.z);
        seg.w += fmaf(acc.w, s4.w, t4.w);
    }
    float* o = &hg[(size_t)cur * EMB + c0];
    unsafeAtomicAdd(o + 0, seg.x);
    unsafeAtomicAdd(o + 1, seg.y);
    unsafeAtomicAdd(o + 2, seg.z);
    unsafeAtomicAdd(o + 3, seg.w);
}

// ---------------------------------------------------------------------------
// Head: OUT[g] = hg[g] @ headW + headb
// ---------------------------------------------------------------------------
__global__ __launch_bounds__(128) void head(const float* __restrict__ HG,
                                            const float* __restrict__ HW,
                                            const float* __restrict__ hb,
                                            float* __restrict__ OUT) {
    __shared__ float hr[EMB];
    const int gph = blockIdx.x;
    const int t   = threadIdx.x;
    hr[t] = HG[(size_t)gph * EMB + t];
    __syncthreads();
    float acc = hb[t];
#pragma unroll 8
    for (int k = 0; k < EMB; ++k) acc = fmaf(hr[k], HW[(size_t)k * EMB + t], acc);
    OUT[(size_t)gph * EMB + t] = acc;
}

extern "C" void kernel_launch(void* const* d_in, const int* in_sizes, int n_in,
                              void* d_out, int out_size, void* d_ws, size_t ws_size,
                              hipStream_t stream) {
    const int*   x     = (const int*)d_in[0];
    const int*   ei    = (const int*)d_in[1];    // [2, E]: src then dst
    const int*   ea    = (const int*)d_in[2];    // [E, 3]
    const int*   batch = (const int*)d_in[3];
    const float* aemb  = (const float*)d_in[4];
    const float* bemb  = (const float*)d_in[5];
    const float* W     = (const float*)d_in[6];
    const float* b     = (const float*)d_in[7];
    const float* root  = (const float*)d_in[8];
    const float* bnm   = (const float*)d_in[9];
    const float* bnv   = (const float*)d_in[10];
    const float* bng   = (const float*)d_in[11];
    const float* bnb   = (const float*)d_in[12];
    const float* hW    = (const float*)d_in[13];
    const float* hb    = (const float*)d_in[14];
    float* out = (float*)d_out;

    const size_t NF = (size_t)N_NODES * EMB;
    const size_t n_float = 2 * NF + (size_t)LAYERS * 512 * EMB
                         + 2 * LAYERS * EMB + N_EDGES
                         + 2 * ((size_t)LAYERS * 16384 / 2 + 64)
                         + (size_t)N_GRAPHS * EMB;
    const size_t n_int   = 3 * (size_t)N_NODES + (N_NODES + 4) + 128 + N_EDGES;
    const size_t need = (n_float + n_int) * sizeof(float);
    if (ws_size < need) return;  // defensive: fail cleanly, don't fault

    float* f     = (float*)d_ws;
    float* bufA  = f;                          f += NF;
    float* bufB  = f;                          f += NF;
    float* combo = f;                          f += (size_t)LAYERS * 512 * EMB;
    float* S     = f;                          f += LAYERS * EMB;
    float* T     = f;                          f += LAYERS * EMB;
    float* enrm  = f;                          f += N_EDGES;
    float* hg    = f;                          f += (size_t)N_GRAPHS * EMB;
    unsigned short* whi = (unsigned short*)f;  f += (size_t)LAYERS * 16384 / 2 + 64;
    unsigned short* wlo = (unsigned short*)f;  f += (size_t)LAYERS * 16384 / 2 + 64;
    int*   ip    = (int*)f;
    int*   dsrc    = ip;                       ip += N_NODES;
    int*   ddst    = ip;                       ip += N_NODES;
    int*   fill    = ip;                       ip += N_NODES;
    int*   rowptr  = ip;                       ip += N_NODES + 4;
    int*   partial = ip;                       ip += 128;
    int*   epk     = ip;                       ip += N_EDGES;

    hipMemsetAsync(dsrc, 0, 3 * (size_t)N_NODES * sizeof(int), stream);
    hipMemsetAsync(hg, 0, (size_t)N_GRAPHS * EMB * sizeof(float), stream);

    bnprep<<<3, 256, 0, stream>>>(bnm, bnv, bng, bnb, S, T);
    wprep<<<(LAYERS * 16384 + 255) / 256, 256, 0, stream>>>(W, whi, wlo);
    combo_k<<<LAYERS * 512, EMB, 0, stream>>>(bemb, combo);
    count_k<<<(N_EDGES + 255) / 256, 256, 0, stream>>>(ei, ei + N_EDGES, dsrc, ddst);
    scan1<<<N_CHUNKS, 256, 0, stream>>>(ddst, partial);
    scan2<<<1, 64, 0, stream>>>(partial);
    scan3<<<N_CHUNKS, 256, 0, stream>>>(ddst, partial, rowptr);
    scatter_k<<<(N_EDGES + 255) / 256, 256, 0, stream>>>(ei, ei + N_EDGES, ea, dsrc,
                                                         rowptr, fill, epk, enrm);

    // L0: encoder fused with GEMM-0 -> XL0 in bufA
    enc_gemm<<<N_NODES / 32, 256, 0, stream>>>(x, aemb, whi, wlo, b, bufA);

    // L0..L3 gathers fused with next layer's GEMM; h stays on-chip.
    float* in    = bufA;
    float* other = bufB;
    for (int l = 0; l < 4; ++l) {
        gather_gemm<<<N_NODES / 32, 256, 0, stream>>>(
            rowptr, epk, enrm, combo + (size_t)l * 512 * EMB, root + l * EMB, dsrc,
            S + l * EMB, T + l * EMB,
            whi + (size_t)(l + 1) * 16384, wlo + (size_t)(l + 1) * 16384,
            b + (l + 1) * EMB, /*XLin=*/in, /*XLout=*/other);
        float* t0 = in; in = other; other = t0;
    }

    // L4 gather fused with BN4 + segmented pooling into hg
    gather_pool<<<N_NODES / 64, 256, 0, stream>>>(
        rowptr, epk, enrm, combo + (size_t)4 * 512 * EMB, root + 4 * EMB, dsrc,
        S + 4 * EMB, T + 4 * EMB, batch, /*XLin=*/in, hg);

    head<<<N_GRAPHS, 128, 0, stream>>>(hg, hW, hb, out);
}

// Round 7
// 735.562 us; speedup vs baseline: 8.3435x; 1.0221x over previous
//
#include <hip/hip_runtime.h>
#include <hip/hip_bf16.h>

#define N_NODES 200000
#define N_EDGES 600000
#define N_GRAPHS 4000
#define EMB 128
#define LAYERS 5
#define BN_EPS 1e-5f

#define SCAN_CHUNK 2048                   // 256 threads x 8
#define N_CHUNKS ((N_NODES + SCAN_CHUNK - 1) / SCAN_CHUNK)   // 98

typedef __attribute__((ext_vector_type(8))) short short8;   // 8 bf16 (4 VGPRs)
typedef __attribute__((ext_vector_type(4))) float float4v;  // MFMA C/D

// split f32 -> bf16 hi (truncate) + bf16 lo (truncate of residual)
__device__ __forceinline__ void bf16split(float f, unsigned short& hi, unsigned short& lo) {
    unsigned u = __float_as_uint(f);
    hi = (unsigned short)(u >> 16);
    float hf = __uint_as_float((unsigned)hi << 16);
    lo = (unsigned short)(__float_as_uint(f - hf) >> 16);
}

// ---------------------------------------------------------------------------
// BN precompute: S = gamma/sqrt(var+eps), T = beta - mean*S
// ---------------------------------------------------------------------------
__global__ void bnprep(const float* __restrict__ mean, const float* __restrict__ var,
                       const float* __restrict__ gamma, const float* __restrict__ beta,
                       float* __restrict__ S, float* __restrict__ T) {
    int i = blockIdx.x * blockDim.x + threadIdx.x;
    if (i < LAYERS * EMB) {
        float s = gamma[i] / sqrtf(var[i] + BN_EPS);
        S[i] = s;
        T[i] = beta[i] - mean[i] * s;
    }
}

// ---------------------------------------------------------------------------
// W prep: split fp32 W[l][k][n] into bf16 hi/lo in MFMA B-fragment swizzled
// order: off = l*16384 + ((ks*8+ct)*64 + lane)*8 + j
//   ks=k>>5, ct=n>>4, lane=((k>>3)&3)*16+(n&15), j=k&7
// ---------------------------------------------------------------------------
__global__ void wprep(const float* __restrict__ W, unsigned short* __restrict__ whi,
                      unsigned short* __restrict__ wlo) {
    int idx = blockIdx.x * 256 + threadIdx.x;
    if (idx >= LAYERS * 16384) return;
    const int l = idx >> 14, rem = idx & 16383;
    const int k = rem >> 7, n = rem & 127;
    unsigned short hi, lo;
    bf16split(W[idx], hi, lo);
    const int off = (l << 14) + ((((k >> 5) * 8 + (n >> 4)) * 64
                    + ((k >> 3) & 3) * 16 + (n & 15)) << 3) + (k & 7);
    whi[off] = hi;
    wlo[off] = lo;
}

// ---------------------------------------------------------------------------
// Bond-combo table: combo[l][c][ch] = sum_f bond_emb[l,f,a_f(c)][ch]
// ---------------------------------------------------------------------------
__global__ void combo_k(const float* __restrict__ bemb, float* __restrict__ combo) {
    const int l = blockIdx.x >> 9;
    const int c = blockIdx.x & 511;
    const int a0 = c & 7, a1 = (c >> 3) & 7, a2 = c >> 6;
    const int t = threadIdx.x;
    combo[(size_t)blockIdx.x * EMB + t] =
        bemb[(size_t)((l * 3 + 0) * 8 + a0) * EMB + t] +
        bemb[(size_t)((l * 3 + 1) * 8 + a1) * EMB + t] +
        bemb[(size_t)((l * 3 + 2) * 8 + a2) * EMB + t];
}

// ---------------------------------------------------------------------------
// Edge histogram: src-degree and dst-degree
// ---------------------------------------------------------------------------
__global__ void count_k(const int* __restrict__ srcs, const int* __restrict__ dsts,
                        int* __restrict__ dsrc, int* __restrict__ ddst) {
    int e = blockIdx.x * blockDim.x + threadIdx.x;
    if (e < N_EDGES) {
        atomicAdd(&dsrc[srcs[e]], 1);
        atomicAdd(&ddst[dsts[e]], 1);
    }
}

// ---------------------------------------------------------------------------
// 3-phase exclusive scan of ddst -> rowptr
// ---------------------------------------------------------------------------
__global__ __launch_bounds__(256) void scan1(const int* __restrict__ deg, int* __restrict__ partial) {
    __shared__ int sd[256];
    const int base = blockIdx.x * SCAN_CHUNK + threadIdx.x * 8;
    int s = 0;
#pragma unroll
    for (int i = 0; i < 8; ++i) { int idx = base + i; s += (idx < N_NODES) ? deg[idx] : 0; }
    sd[threadIdx.x] = s; __syncthreads();
    for (int off = 128; off > 0; off >>= 1) {
        if (threadIdx.x < off) sd[threadIdx.x] += sd[threadIdx.x + off];
        __syncthreads();
    }
    if (threadIdx.x == 0) partial[blockIdx.x] = sd[0];
}

__global__ void scan2(int* __restrict__ partial) {
    if (threadIdx.x == 0) {
        int acc = 0;
        for (int i = 0; i < N_CHUNKS; ++i) { int v = partial[i]; partial[i] = acc; acc += v; }
    }
}

__global__ __launch_bounds__(256) void scan3(const int* __restrict__ deg,
                                             const int* __restrict__ partial,
                                             int* __restrict__ rowptr) {
    __shared__ int sd[256];
    const int tid = threadIdx.x;
    const int base = blockIdx.x * SCAN_CHUNK + tid * 8;
    int loc[8]; int s = 0;
#pragma unroll
    for (int i = 0; i < 8; ++i) { int idx = base + i; loc[i] = (idx < N_NODES) ? deg[idx] : 0; s += loc[i]; }
    sd[tid] = s; __syncthreads();
    for (int off = 1; off < 256; off <<= 1) {
        int v = (tid >= off) ? sd[tid - off] : 0;
        __syncthreads();
        sd[tid] += v;
        __syncthreads();
    }
    int excl = partial[blockIdx.x] + sd[tid] - s;
#pragma unroll
    for (int i = 0; i < 8; ++i) {
        int idx = base + i;
        if (idx < N_NODES) { rowptr[idx] = excl; excl += loc[i]; }
    }
    if (blockIdx.x == 0 && tid == 0) rowptr[N_NODES] = N_EDGES;
}

// ---------------------------------------------------------------------------
// Scatter edges into dst-CSR. Record: epk = src | combo<<18 ; enrm = norm.
// ---------------------------------------------------------------------------
__global__ void scatter_k(const int* __restrict__ srcs, const int* __restrict__ dsts,
                          const int* __restrict__ eattr, const int* __restrict__ dsrc,
                          const int* __restrict__ rowptr, int* __restrict__ fill,
                          int* __restrict__ epk, float* __restrict__ enrm) {
    int e = blockIdx.x * blockDim.x + threadIdx.x;
    if (e >= N_EDGES) return;
    const int s = srcs[e];
    const int d = dsts[e];
    const int pos = rowptr[d] + atomicAdd(&fill[d], 1);
    const int c = eattr[e * 3] | (eattr[e * 3 + 1] << 3) | (eattr[e * 3 + 2] << 6);
    epk[pos] = s | (c << 18);
    enrm[pos] = rsqrtf((float)(dsrc[s] + 1) * (float)(dsrc[d] + 1));
}

// ---------------------------------------------------------------------------
// Graph boundaries from sorted batch
// ---------------------------------------------------------------------------
__global__ void gboundary(const int* __restrict__ batch, int* __restrict__ gptr) {
    int g = blockIdx.x * blockDim.x + threadIdx.x;
    if (g > N_GRAPHS) return;
    if (g == N_GRAPHS) { gptr[g] = N_NODES; return; }
    int lo = 0, hi = N_NODES;
    while (lo < hi) {
        int mid = (lo + hi) >> 1;
        if (batch[mid] < g) lo = mid + 1; else hi = mid;
    }
    gptr[g] = lo;
}

// ---------------------------------------------------------------------------
// MFMA phase for 1024-thread blocks: 32 rows x 128 cols, 16 waves, each wave
// one 16x16 C-tile over K=128 (4 ksteps x 3 split-terms).
// A-frag: A[m=lane&15][k=(lane>>4)*8+j]; B pre-swizzled; C/D col=lane&15,
// row=(lane>>4)*4+reg.
// ---------------------------------------------------------------------------
__device__ __forceinline__ void mfma_tile32(
    const unsigned short (*Ah)[136], const unsigned short (*Al)[136],
    const short8* __restrict__ Bh, const short8* __restrict__ Bl,
    const float* __restrict__ bias, float* __restrict__ XLout,
    size_t rows, int tid) {
    const int wave = tid >> 6;          // 0..15
    const int lane = tid & 63;
    const int quad = lane >> 4;
    const int n15  = lane & 15;
    const int rt   = wave & 1;          // row-tile
    const int ct   = wave >> 1;         // col-tile 0..7
    const int arow = rt * 16 + n15;

    float4v acc = (float4v)(0.f);
#pragma unroll
    for (int ks = 0; ks < 4; ++ks) {
        const int k0 = ks * 32 + quad * 8;
        const short8 ah = *(const short8*)&Ah[arow][k0];
        const short8 al = *(const short8*)&Al[arow][k0];
        const short8 bh = Bh[(ks * 8 + ct) * 64 + lane];
        const short8 bl = Bl[(ks * 8 + ct) * 64 + lane];
        acc = __builtin_amdgcn_mfma_f32_16x16x32_bf16(ah, bh, acc, 0, 0, 0);
        acc = __builtin_amdgcn_mfma_f32_16x16x32_bf16(ah, bl, acc, 0, 0, 0);
        acc = __builtin_amdgcn_mfma_f32_16x16x32_bf16(al, bh, acc, 0, 0, 0);
    }

    const size_t rowBase = rows + rt * 16 + quad * 4;
    const int col = ct * 16 + n15;
    const float bc = bias[col];
#pragma unroll
    for (int r = 0; r < 4; ++r)
        XLout[(rowBase + r) * EMB + col] = acc[r] + bc;
}

// ---------------------------------------------------------------------------
// Fused atom-encoder + GEMM layer 0 (1024 threads): 32 half-waves x 1 row.
// ---------------------------------------------------------------------------
__global__ __launch_bounds__(1024, 8) void enc_gemm(
    const int* __restrict__ x, const float* __restrict__ aemb,
    const unsigned short* __restrict__ whi, const unsigned short* __restrict__ wlo,
    const float* __restrict__ bias, float* __restrict__ XL) {
    __shared__ unsigned short Ah[32][136];
    __shared__ unsigned short Al[32][136];
    const int tid = threadIdx.x;
    const int g = tid & 31, hw = tid >> 5;     // 32 half-waves
    const int c0 = g * 4;
    const size_t rows = (size_t)blockIdx.x * 32;

    {
        const size_t n = rows + hw;
        float4 acc = make_float4(0.f, 0.f, 0.f, 0.f);
#pragma unroll
        for (int ff = 0; ff < 9; ++ff) {
            const int v = x[n * 9 + ff];
            const float4 e = *(const float4*)&aemb[(size_t)(ff * 64 + v) * EMB + c0];
            acc.x += e.x; acc.y += e.y; acc.z += e.z; acc.w += e.w;
        }
        ushort4 hi, lo;
        bf16split(acc.x, hi.x, lo.x);
        bf16split(acc.y, hi.y, lo.y);
        bf16split(acc.z, hi.z, lo.z);
        bf16split(acc.w, hi.w, lo.w);
        *(ushort4*)&Ah[hw][c0] = hi;
        *(ushort4*)&Al[hw][c0] = lo;
    }
    __syncthreads();
    mfma_tile32(Ah, Al, (const short8*)whi, (const short8*)wlo, bias, XL, rows, tid);
}

// ---------------------------------------------------------------------------
// Fused gather(layer l) + BN_l + ReLU + GEMM(layer l+1) (1024 threads):
// 32 half-waves x 1 node gather -> LDS bf16 split -> 16-wave MFMA.
// ---------------------------------------------------------------------------
__global__ __launch_bounds__(1024, 8) void gather_gemm(
    const int* __restrict__ rowptr, const int* __restrict__ epk,
    const float* __restrict__ enrm, const float* __restrict__ combo,
    const float* __restrict__ root, const int* __restrict__ dsrc,
    const float* __restrict__ bnS, const float* __restrict__ bnT,
    const unsigned short* __restrict__ whi, const unsigned short* __restrict__ wlo,
    const float* __restrict__ bias,
    const float* __restrict__ XLin, float* __restrict__ XLout) {
    __shared__ unsigned short Ah[32][136];
    __shared__ unsigned short Al[32][136];
    const int tid = threadIdx.x;
    const int g = tid & 31, hw = tid >> 5;
    const int c0 = g * 4;
    const size_t rows = (size_t)blockIdx.x * 32;

    {
        const size_t n = rows + hw;
        const float4 r4 = *(const float4*)&root[c0];
        const float4 s4 = *(const float4*)&bnS[c0];
        const float4 t4 = *(const float4*)&bnT[c0];
        const float dinv = 1.0f / (float)(dsrc[n] + 1);
        const float4 xn = *(const float4*)&XLin[n * EMB + c0];
        float4 acc;
        acc.x = fmaxf(xn.x + r4.x, 0.f) * dinv;
        acc.y = fmaxf(xn.y + r4.y, 0.f) * dinv;
        acc.z = fmaxf(xn.z + r4.z, 0.f) * dinv;
        acc.w = fmaxf(xn.w + r4.w, 0.f) * dinv;
        const int beg = rowptr[n], end = rowptr[n + 1];
        int pk = 0; float wgt = 0.f;
        if (beg < end) { pk = epk[beg]; wgt = enrm[beg]; }
        for (int e = beg; e < end; ++e) {
            const int pk_c = pk; const float w_c = wgt;
            if (e + 1 < end) { pk = epk[e + 1]; wgt = enrm[e + 1]; }   // prefetch
            const int s = pk_c & 0x3FFFF;
            const int c = pk_c >> 18;
            const float4 xv = *(const float4*)&XLin[(size_t)s * EMB + c0];
            const float4 cb = *(const float4*)&combo[(size_t)c * EMB + c0];
            acc.x += fmaxf(xv.x + cb.x, 0.f) * w_c;
            acc.y += fmaxf(xv.y + cb.y, 0.f) * w_c;
            acc.z += fmaxf(xv.z + cb.z, 0.f) * w_c;
            acc.w += fmaxf(xv.w + cb.w, 0.f) * w_c;
        }
        float4 h;
        h.x = fmaxf(fmaf(acc.x, s4.x, t4.x), 0.f);
        h.y = fmaxf(fmaf(acc.y, s4.y, t4.y), 0.f);
        h.z = fmaxf(fmaf(acc.z, s4.z, t4.z), 0.f);
        h.w = fmaxf(fmaf(acc.w, s4.w, t4.w), 0.f);
        ushort4 hi, lo;
        bf16split(h.x, hi.x, lo.x);
        bf16split(h.y, hi.y, lo.y);
        bf16split(h.z, hi.z, lo.z);
        bf16split(h.w, hi.w, lo.w);
        *(ushort4*)&Ah[hw][c0] = hi;
        *(ushort4*)&Al[hw][c0] = lo;
    }
    __syncthreads();
    mfma_tile32(Ah, Al, (const short8*)whi, (const short8*)wlo, bias, XLout, rows, tid);
}

// ---------------------------------------------------------------------------
// Fused final gather(layer 4) + BN4 + pool + head. One block per graph
// (batch sorted -> contiguous via gptr). 8 half-waves stride the graph's
// nodes with register partials; LDS reduce; in-block head matvec.
// No global atomics; h4 and hg never touch HBM.
// ---------------------------------------------------------------------------
__global__ __launch_bounds__(256) void gather_pool_head(
    const int* __restrict__ rowptr, const int* __restrict__ epk,
    const float* __restrict__ enrm, const float* __restrict__ combo,
    const float* __restrict__ root, const int* __restrict__ dsrc,
    const float* __restrict__ S4, const float* __restrict__ T4,
    const int* __restrict__ gptr, const float* __restrict__ XLin,
    const float* __restrict__ HW, const float* __restrict__ hb,
    float* __restrict__ OUT) {
    __shared__ float red[8][EMB];
    __shared__ float hr[EMB];
    const int gph = blockIdx.x;
    const int g = threadIdx.x & 31, hw = threadIdx.x >> 5;   // 8 half-waves
    const int c0 = g * 4;
    const int nbeg = gptr[gph], nend = gptr[gph + 1];

    const float4 r4 = *(const float4*)&root[c0];
    const float4 s4 = *(const float4*)&S4[c0];
    const float4 t4 = *(const float4*)&T4[c0];

    float4 seg = make_float4(0.f, 0.f, 0.f, 0.f);
    for (int n = nbeg + hw; n < nend; n += 8) {
        const float dinv = 1.0f / (float)(dsrc[n] + 1);
        const float4 xn = *(const float4*)&XLin[(size_t)n * EMB + c0];
        float4 acc;
        acc.x = fmaxf(xn.x + r4.x, 0.f) * dinv;
        acc.y = fmaxf(xn.y + r4.y, 0.f) * dinv;
        acc.z = fmaxf(xn.z + r4.z, 0.f) * dinv;
        acc.w = fmaxf(xn.w + r4.w, 0.f) * dinv;
        const int beg = rowptr[n], end = rowptr[n + 1];
        int pk = 0; float wgt = 0.f;
        if (beg < end) { pk = epk[beg]; wgt = enrm[beg]; }
        for (int e = beg; e < end; ++e) {
            const int pk_c = pk; const float w_c = wgt;
            if (e + 1 < end) { pk = epk[e + 1]; wgt = enrm[e + 1]; }
            const int s = pk_c & 0x3FFFF;
            const int c = pk_c >> 18;
            const float4 xv = *(const float4*)&XLin[(size_t)s * EMB + c0];
            const float4 cb = *(const float4*)&combo[(size_t)c * EMB + c0];
            acc.x += fmaxf(xv.x + cb.x, 0.f) * w_c;
            acc.y += fmaxf(xv.y + cb.y, 0.f) * w_c;
            acc.z += fmaxf(xv.z + cb.z, 0.f) * w_c;
            acc.w += fmaxf(xv.w + cb.w, 0.f) * w_c;
        }
        // BN4 (no relu), accumulate per-graph partial in registers
        seg.x += fmaf(acc.x, s4.x, t4.x);
        seg.y += fmaf(acc.y, s4.y, t4.y);
        seg.z += fmaf(acc.z, s4.z, t4.z);
        seg.w += fmaf(acc.w, s4.w, t4.w);
    }
    *(float4*)&red[hw][c0] = seg;
    __syncthreads();

    const int t = threadIdx.x;
    if (t < EMB) {
        float v = 0.f;
#pragma unroll
        for (int r = 0; r < 8; ++r) v += red[r][t];
        hr[t] = v;
    }
    __syncthreads();
    if (t < EMB) {
        float o = hb[t];
#pragma unroll 8
        for (int k = 0; k < EMB; ++k) o = fmaf(hr[k], HW[(size_t)k * EMB + t], o);
        OUT[(size_t)gph * EMB + t] = o;
    }
}

extern "C" void kernel_launch(void* const* d_in, const int* in_sizes, int n_in,
                              void* d_out, int out_size, void* d_ws, size_t ws_size,
                              hipStream_t stream) {
    const int*   x     = (const int*)d_in[0];
    const int*   ei    = (const int*)d_in[1];    // [2, E]: src then dst
    const int*   ea    = (const int*)d_in[2];    // [E, 3]
    const int*   batch = (const int*)d_in[3];
    const float* aemb  = (const float*)d_in[4];
    const float* bemb  = (const float*)d_in[5];
    const float* W     = (const float*)d_in[6];
    const float* b     = (const float*)d_in[7];
    const float* root  = (const float*)d_in[8];
    const float* bnm   = (const float*)d_in[9];
    const float* bnv   = (const float*)d_in[10];
    const float* bng   = (const float*)d_in[11];
    const float* bnb   = (const float*)d_in[12];
    const float* hW    = (const float*)d_in[13];
    const float* hb    = (const float*)d_in[14];
    float* out = (float*)d_out;

    const size_t NF = (size_t)N_NODES * EMB;
    const size_t n_float = 2 * NF + (size_t)LAYERS * 512 * EMB
                         + 2 * LAYERS * EMB + N_EDGES
                         + 2 * ((size_t)LAYERS * 16384 / 2 + 64);
    const size_t n_int   = 3 * (size_t)N_NODES + (N_NODES + 4) + 128
                         + (N_GRAPHS + 4) + N_EDGES;
    const size_t need = (n_float + n_int) * sizeof(float);
    if (ws_size < need) return;  // defensive: fail cleanly, don't fault

    float* f     = (float*)d_ws;
    float* bufA  = f;                          f += NF;
    float* bufB  = f;                          f += NF;
    float* combo = f;                          f += (size_t)LAYERS * 512 * EMB;
    float* S     = f;                          f += LAYERS * EMB;
    float* T     = f;                          f += LAYERS * EMB;
    float* enrm  = f;                          f += N_EDGES;
    unsigned short* whi = (unsigned short*)f;  f += (size_t)LAYERS * 16384 / 2 + 64;
    unsigned short* wlo = (unsigned short*)f;  f += (size_t)LAYERS * 16384 / 2 + 64;
    int*   ip    = (int*)f;
    int*   dsrc    = ip;                       ip += N_NODES;
    int*   ddst    = ip;                       ip += N_NODES;
    int*   fill    = ip;                       ip += N_NODES;
    int*   rowptr  = ip;                       ip += N_NODES + 4;
    int*   partial = ip;                       ip += 128;
    int*   gptr    = ip;                       ip += N_GRAPHS + 4;
    int*   epk     = ip;                       ip += N_EDGES;

    hipMemsetAsync(dsrc, 0, 3 * (size_t)N_NODES * sizeof(int), stream);

    bnprep<<<3, 256, 0, stream>>>(bnm, bnv, bng, bnb, S, T);
    wprep<<<(LAYERS * 16384 + 255) / 256, 256, 0, stream>>>(W, whi, wlo);
    combo_k<<<LAYERS * 512, EMB, 0, stream>>>(bemb, combo);
    count_k<<<(N_EDGES + 255) / 256, 256, 0, stream>>>(ei, ei + N_EDGES, dsrc, ddst);
    scan1<<<N_CHUNKS, 256, 0, stream>>>(ddst, partial);
    scan2<<<1, 64, 0, stream>>>(partial);
    scan3<<<N_CHUNKS, 256, 0, stream>>>(ddst, partial, rowptr);
    scatter_k<<<(N_EDGES + 255) / 256, 256, 0, stream>>>(ei, ei + N_EDGES, ea, dsrc,
                                                         rowptr, fill, epk, enrm);
    gboundary<<<(N_GRAPHS + 256) / 256, 256, 0, stream>>>(batch, gptr);

    // L0: encoder fused with GEMM-0 -> XL0 in bufA
    enc_gemm<<<N_NODES / 32, 1024, 0, stream>>>(x, aemb, whi, wlo, b, bufA);

    // L0..L3 gathers fused with next layer's GEMM; h stays on-chip.
    float* in    = bufA;
    float* other = bufB;
    for (int l = 0; l < 4; ++l) {
        gather_gemm<<<N_NODES / 32, 1024, 0, stream>>>(
            rowptr, epk, enrm, combo + (size_t)l * 512 * EMB, root + l * EMB, dsrc,
            S + l * EMB, T + l * EMB,
            whi + (size_t)(l + 1) * 16384, wlo + (size_t)(l + 1) * 16384,
            b + (l + 1) * EMB, /*XLin=*/in, /*XLout=*/other);
        float* t0 = in; in = other; other = t0;
    }

    // L4 gather fused with BN4 + pool + head, one block per graph, no atomics
    gather_pool_head<<<N_GRAPHS, 256, 0, stream>>>(
        rowptr, epk, enrm, combo + (size_t)4 * 512 * EMB, root + 4 * EMB, dsrc,
        S + 4 * EMB, T + 4 * EMB, gptr, /*XLin=*/in, hW, hb, out);
}